// Round 1
// baseline (1585.589 us; speedup 1.0000x reference)
//
#include <hip/hip_runtime.h>
#include <hip/hip_bf16.h>

typedef unsigned short ushort_t;

__device__ __forceinline__ float bf2f(ushort_t u){ return __uint_as_float(((unsigned)u)<<16); }
__device__ __forceinline__ ushort_t f2bf(float f){
  unsigned x = __float_as_uint(f);
  unsigned r = (x + 0x7fffu + ((x>>16)&1u)) >> 16;
  return (ushort_t)r;
}

// ---------------------------------------------------------------------------
// Phase 1: wl[i] = W_i @ attn_l_i, wr[i] = W_i @ attn_r_i  (8 x 128 each)
// bsum[j] = sum_i lam[i/2] * bias[i][j]
// ---------------------------------------------------------------------------
__global__ void wlr_kernel(const float* __restrict__ W, const float* __restrict__ al,
                           const float* __restrict__ ar, const float* __restrict__ bias,
                           const float* __restrict__ lam,
                           float* __restrict__ wl, float* __restrict__ wr,
                           float* __restrict__ bsum) {
  int i = blockIdx.x, j = threadIdx.x;         // 8 blocks x 128 threads
  const float* Wi  = W + ((size_t)i*128 + j)*128;
  const float* ali = al + i*128;
  const float* ari = ar + i*128;
  float sl = 0.f, sr = 0.f;
  for (int k = 0; k < 128; ++k) { float w = Wi[k]; sl += w*ali[k]; sr += w*ari[k]; }
  wl[i*128+j] = sl; wr[i*128+j] = sr;
  if (i == 0) {
    float b = 0.f;
    for (int t = 0; t < 8; ++t) b += lam[t>>1]*bias[t*128+j];
    bsum[j] = b;
  }
}

// ---------------------------------------------------------------------------
// Phase 2: per-node attention scalars. wave per node.
// el[i][n] = dot(x_src_i[n], wl[i]) ; x_src_i = feat_src for i in {0,1,4,5}
// er[i][n] = dot(feat_dst[n], wr[i])  (x_dst == feat_dst for every conv)
// ---------------------------------------------------------------------------
__global__ __launch_bounds__(256) void elr_kernel(const float* __restrict__ fs,
    const float* __restrict__ fd, const float* __restrict__ wl, const float* __restrict__ wr,
    float* __restrict__ el, float* __restrict__ er, int n) {
  int wid  = (blockIdx.x*256 + threadIdx.x) >> 6;
  int lane = threadIdx.x & 63;
  if (wid >= n) return;
  float2 s = *(const float2*)(fs + (size_t)wid*128 + lane*2);
  float2 d = *(const float2*)(fd + (size_t)wid*128 + lane*2);
#pragma unroll
  for (int i = 0; i < 8; ++i) {
    float2 wlv = *(const float2*)(wl + i*128 + lane*2);
    float2 wrv = *(const float2*)(wr + i*128 + lane*2);
    bool use_s = (i==0)||(i==1)||(i==4)||(i==5);
    float xx = use_s ? s.x : d.x;
    float xy = use_s ? s.y : d.y;
    float vl = xx*wlv.x + xy*wlv.y;
    float vr = d.x*wrv.x + d.y*wrv.y;
#pragma unroll
    for (int off = 32; off; off >>= 1) { vl += __shfl_xor(vl, off); vr += __shfl_xor(vr, off); }
    if (lane == 0) { el[(size_t)i*n + wid] = vl; er[(size_t)i*n + wid] = vr; }
  }
}

// ---------------------------------------------------------------------------
// CSR build over 4 graphs jointly (each graph has exactly e edges).
// graph 0: intra fwd (s=ia_s,d=ia_d), 1: inter fwd, 2: intra rev, 3: inter rev
// ---------------------------------------------------------------------------
__global__ __launch_bounds__(256) void hist_kernel(const int* __restrict__ ia_s,
    const int* __restrict__ ia_d, const int* __restrict__ ie_s, const int* __restrict__ ie_d,
    int* __restrict__ counts, int n, int e) {
  int t = blockIdx.x*256 + threadIdx.x;
  if (t >= 4*e) return;
  int g = t / e, idx = t - g*e;
  int d;
  if      (g == 0) d = ia_d[idx];
  else if (g == 1) d = ie_d[idx];
  else if (g == 2) d = ia_s[idx];
  else             d = ie_s[idx];
  atomicAdd(&counts[g*n + d], 1);
}

__global__ __launch_bounds__(256) void scan_local_kernel(const int* __restrict__ counts,
    int* __restrict__ rowptr, int* __restrict__ bsums, int total) {
  __shared__ int sh[256];
  int base = blockIdx.x*1024;
  int tid = threadIdx.x;
  int v[4]; int s = 0;
#pragma unroll
  for (int q = 0; q < 4; ++q) { int idx = base + tid*4 + q; int x = (idx < total) ? counts[idx] : 0; v[q] = x; s += x; }
  sh[tid] = s; __syncthreads();
  for (int off = 1; off < 256; off <<= 1) {
    int t2 = (tid >= off) ? sh[tid-off] : 0;
    __syncthreads();
    sh[tid] += t2;
    __syncthreads();
  }
  if (tid == 255) bsums[blockIdx.x] = sh[255];
  int run = sh[tid] - s;
#pragma unroll
  for (int q = 0; q < 4; ++q) { int idx = base + tid*4 + q; if (idx < total) rowptr[idx] = run; run += v[q]; }
}

__global__ void scan_bsums_kernel(int* __restrict__ bsums, int nb) {
  __shared__ int sh[1024];
  int tid = threadIdx.x;
  int v = (tid < nb) ? bsums[tid] : 0;
  sh[tid] = v; __syncthreads();
  for (int off = 1; off < 1024; off <<= 1) {
    int t2 = (tid >= off) ? sh[tid-off] : 0;
    __syncthreads();
    sh[tid] += t2;
    __syncthreads();
  }
  if (tid < nb) bsums[tid] = sh[tid] - v;   // exclusive
}

__global__ void scan_add_kernel(int* __restrict__ rowptr, const int* __restrict__ bsums,
                                int total, int grand) {
  int idx = blockIdx.x*blockDim.x + threadIdx.x;
  if (idx < total) rowptr[idx] += bsums[idx >> 10];
  if (idx == total) rowptr[total] = grand;
}

__global__ __launch_bounds__(256) void fill_kernel(const int* __restrict__ ia_s,
    const int* __restrict__ ia_d, const int* __restrict__ ie_s, const int* __restrict__ ie_d,
    const int* __restrict__ rowptr, int* __restrict__ cursor, int* __restrict__ col,
    int n, int e) {
  int t = blockIdx.x*256 + threadIdx.x;
  if (t >= 4*e) return;
  int g = t / e, idx = t - g*e;
  int d, s;
  if      (g == 0) { d = ia_d[idx]; s = ia_s[idx]; }
  else if (g == 1) { d = ie_d[idx]; s = ie_s[idx]; }
  else if (g == 2) { d = ia_s[idx]; s = ia_d[idx]; }
  else             { d = ie_s[idx]; s = ie_d[idx]; }
  int pos = atomicAdd(&cursor[g*n + d], 1);
  col[rowptr[g*n + d] + pos] = s;
}

// ---------------------------------------------------------------------------
// Phase 3: per-dst softmax + feature aggregation. Wave per dst, 2 gats/graph.
// gatA gathers feat_src, gatB gathers feat_dst. aggX layout [n][2][128] bf16.
// ---------------------------------------------------------------------------
__global__ __launch_bounds__(256) void agg_kernel(const float* __restrict__ fs,
    const float* __restrict__ fd, const float* __restrict__ el, const float* __restrict__ er,
    const int* __restrict__ rowptr, const int* __restrict__ col,
    ushort_t* __restrict__ aggX, int g, int gatA, int gatB, int n) {
  int d    = (blockIdx.x*256 + threadIdx.x) >> 6;
  int lane = threadIdx.x & 63;
  if (d >= n) return;
  int row = rowptr[g*n + d], end = rowptr[g*n + d + 1];
  float aAx = 0.f, aAy = 0.f, aBx = 0.f, aBy = 0.f;
  if (end > row) {
    float erA = er[(size_t)gatA*n + d], erB = er[(size_t)gatB*n + d];
    const float* elA = el + (size_t)gatA*n;
    const float* elB = el + (size_t)gatB*n;
    float mA = -1e30f, mB = -1e30f;
    for (int e2 = row; e2 < end; ++e2) {
      int s = col[e2];
      float ea = elA[s] + erA; ea = (ea > 0.f) ? ea : 0.2f*ea;
      float eb = elB[s] + erB; eb = (eb > 0.f) ? eb : 0.2f*eb;
      mA = fmaxf(mA, ea); mB = fmaxf(mB, eb);
    }
    float dA = 0.f, dB = 0.f;
    for (int e2 = row; e2 < end; ++e2) {
      int s = col[e2];
      float ea = elA[s] + erA; ea = (ea > 0.f) ? ea : 0.2f*ea;
      float eb = elB[s] + erB; eb = (eb > 0.f) ? eb : 0.2f*eb;
      float pa = __expf(ea - mA), pb = __expf(eb - mB);
      dA += pa; dB += pb;
      float2 xs = *(const float2*)(fs + (size_t)s*128 + lane*2);
      float2 xd = *(const float2*)(fd + (size_t)s*128 + lane*2);
      aAx += pa*xs.x; aAy += pa*xs.y;
      aBx += pb*xd.x; aBy += pb*xd.y;
    }
    float rA = 1.f/fmaxf(dA, 1e-9f), rB = 1.f/fmaxf(dB, 1e-9f);
    aAx *= rA; aAy *= rA; aBx *= rB; aBy *= rB;
  }
  ushort2 uA; uA.x = f2bf(aAx); uA.y = f2bf(aAy);
  ushort2 uB; uB.x = f2bf(aBx); uB.y = f2bf(aBy);
  *(ushort2*)(aggX + ((size_t)d*2 + 0)*128 + lane*2) = uA;
  *(ushort2*)(aggX + ((size_t)d*2 + 1)*128 + lane*2) = uB;
}

// ---------------------------------------------------------------------------
// Phase 4: out (+)= A[N x 256] @ Wc[256 x 128], Wc[s*128+k][j] = c_s*W[gat_s][k][j]
// first pass also adds residual 2*(sum lam)*feat_dst + bsum.
// Tile 128 rows x 128 cols, 256 threads, 8x8 per thread.
// ---------------------------------------------------------------------------
__global__ __launch_bounds__(256) void gemm_kernel(const ushort_t* __restrict__ A,
    const float* __restrict__ W, const float* __restrict__ lam, const float* __restrict__ fd,
    const float* __restrict__ bsum, float* __restrict__ out,
    int n, int gatA, int gatB, int first) {
  __shared__ float As[16][128];
  __shared__ float Bs[16][132];
  int t = threadIdx.x;
  int base = blockIdx.x*128;
  int tx = t & 15, ty = t >> 4;
  float cA = lam[gatA>>1], cB = lam[gatB>>1];
  float acc[8][8];
#pragma unroll
  for (int q = 0; q < 8; ++q)
#pragma unroll
    for (int j = 0; j < 8; ++j) acc[q][j] = 0.f;

  for (int k0 = 0; k0 < 256; k0 += 16) {
    { // A tile: 128 rows x 16 k (bf16 -> f32), transposed into As[k][r]
      int r = t >> 1, kq = (t & 1)*8;
      int gr = base + r;
      float av[8];
      if (gr < n) {
        const ushort_t* ap = A + (size_t)gr*256 + k0 + kq;
        ushort4 u0 = *(const ushort4*)ap;
        ushort4 u1 = *(const ushort4*)(ap + 4);
        av[0]=bf2f(u0.x); av[1]=bf2f(u0.y); av[2]=bf2f(u0.z); av[3]=bf2f(u0.w);
        av[4]=bf2f(u1.x); av[5]=bf2f(u1.y); av[6]=bf2f(u1.z); av[7]=bf2f(u1.w);
      } else {
#pragma unroll
        for (int q = 0; q < 8; ++q) av[q] = 0.f;
      }
#pragma unroll
      for (int q = 0; q < 8; ++q) As[kq+q][r] = av[q];
    }
    { // B tile: 16 k x 128 j, scaled by lam coefficient
      int kk = t >> 4, j0 = (t & 15)*8;
      int kg = k0 + kk; int sHalf = kg >> 7; int kloc = kg & 127;
      int gat = sHalf ? gatB : gatA;
      float c = sHalf ? cB : cA;
      const float* wp = W + ((size_t)gat*128 + kloc)*128 + j0;
      float4 w0 = *(const float4*)wp;
      float4 w1 = *(const float4*)(wp + 4);
      Bs[kk][j0+0]=c*w0.x; Bs[kk][j0+1]=c*w0.y; Bs[kk][j0+2]=c*w0.z; Bs[kk][j0+3]=c*w0.w;
      Bs[kk][j0+4]=c*w1.x; Bs[kk][j0+5]=c*w1.y; Bs[kk][j0+6]=c*w1.z; Bs[kk][j0+7]=c*w1.w;
    }
    __syncthreads();
#pragma unroll
    for (int kk = 0; kk < 16; ++kk) {
      float a[8], b[8];
#pragma unroll
      for (int q = 0; q < 8; ++q) a[q] = As[kk][ty*8+q];
#pragma unroll
      for (int j = 0; j < 8; ++j) b[j] = Bs[kk][tx*8+j];
#pragma unroll
      for (int q = 0; q < 8; ++q)
#pragma unroll
        for (int j = 0; j < 8; ++j) acc[q][j] += a[q]*b[j];
    }
    __syncthreads();
  }

  float rc = 2.f*(lam[0] + lam[1] + lam[2] + lam[3]);
#pragma unroll
  for (int q = 0; q < 8; ++q) {
    int gr = base + ty*8 + q;
    if (gr >= n) break;
    float* op = out + (size_t)gr*128 + tx*8;
    const float* fp = fd + (size_t)gr*128 + tx*8;
#pragma unroll
    for (int j = 0; j < 8; ++j) {
      float v = acc[q][j];
      if (first) v += rc*fp[j] + bsum[tx*8+j];
      else       v += op[j];
      op[j] = v;
    }
  }
}

// ---------------------------------------------------------------------------
extern "C" void kernel_launch(void* const* d_in, const int* in_sizes, int n_in,
                              void* d_out, int out_size, void* d_ws, size_t ws_size,
                              hipStream_t stream) {
  const float* fs  = (const float*)d_in[0];
  const float* fd  = (const float*)d_in[1];
  const int* ia_s  = (const int*)d_in[2];
  const int* ia_d  = (const int*)d_in[3];
  const int* ie_s  = (const int*)d_in[4];
  const int* ie_d  = (const int*)d_in[5];
  const float* W   = (const float*)d_in[6];
  const float* al  = (const float*)d_in[7];
  const float* ar  = (const float*)d_in[8];
  const float* bias= (const float*)d_in[9];
  const float* lam = (const float*)d_in[10];
  int n = in_sizes[0] / 128;
  int e = in_sizes[2];
  float* out = (float*)d_out;

  char* ws = (char*)d_ws;
  size_t off = 0;
  auto alloc = [&](size_t bytes) -> char* { char* p = ws + off; off += (bytes + 255) & ~(size_t)255; return p; };
  float* wl      = (float*)alloc((size_t)8*128*4);
  float* wr      = (float*)alloc((size_t)8*128*4);
  float* bsum    = (float*)alloc(128*4);
  float* el      = (float*)alloc((size_t)8*n*4);
  float* er      = (float*)alloc((size_t)8*n*4);
  int*   counts  = (int*)alloc((size_t)4*n*4);
  int*   rowptr  = (int*)alloc(((size_t)4*n + 1)*4);
  int*   bsums   = (int*)alloc(4096);
  int*   colv    = (int*)alloc((size_t)4*e*4);
  ushort_t* aggX = (ushort_t*)alloc((size_t)n*256*2);
  (void)ws_size; (void)n_in; (void)out_size;

  hipLaunchKernelGGL(wlr_kernel, dim3(8), dim3(128), 0, stream, W, al, ar, bias, lam, wl, wr, bsum);
  hipLaunchKernelGGL(elr_kernel, dim3((n+3)/4), dim3(256), 0, stream, fs, fd, wl, wr, el, er, n);

  hipMemsetAsync(counts, 0, (size_t)4*n*4, stream);
  hipLaunchKernelGGL(hist_kernel, dim3((4*e+255)/256), dim3(256), 0, stream,
                     ia_s, ia_d, ie_s, ie_d, counts, n, e);
  int total = 4*n;
  int nb = (total + 1023)/1024;
  hipLaunchKernelGGL(scan_local_kernel, dim3(nb), dim3(256), 0, stream, counts, rowptr, bsums, total);
  hipLaunchKernelGGL(scan_bsums_kernel, dim3(1), dim3(1024), 0, stream, bsums, nb);
  hipLaunchKernelGGL(scan_add_kernel, dim3((total+1+255)/256), dim3(256), 0, stream, rowptr, bsums, total, 4*e);
  hipMemsetAsync(counts, 0, (size_t)4*n*4, stream);
  hipLaunchKernelGGL(fill_kernel, dim3((4*e+255)/256), dim3(256), 0, stream,
                     ia_s, ia_d, ie_s, ie_d, rowptr, counts, colv, n, e);

  const int gA[4] = {0, 1, 4, 5};
  const int gB[4] = {2, 3, 6, 7};
  for (int g = 0; g < 4; ++g) {
    hipLaunchKernelGGL(agg_kernel, dim3((n+3)/4), dim3(256), 0, stream,
                       fs, fd, el, er, rowptr, colv, aggX, g, gA[g], gB[g], n);
    hipLaunchKernelGGL(gemm_kernel, dim3((n+127)/128), dim3(256), 0, stream,
                       aggX, W, lam, fd, bsum, out, n, gA[g], gB[g], (g==0) ? 1 : 0);
  }
}

// Round 2
// 1075.540 us; speedup vs baseline: 1.4742x; 1.4742x over previous
//
#include <hip/hip_runtime.h>
#include <hip/hip_bf16.h>

typedef unsigned short ushort_t;
typedef __bf16 bf16x8 __attribute__((ext_vector_type(8)));
typedef float f32x4 __attribute__((ext_vector_type(4)));

__device__ __forceinline__ float bf2f(ushort_t u){ return __uint_as_float(((unsigned)u)<<16); }
__device__ __forceinline__ ushort_t f2bf(float f){
  unsigned x = __float_as_uint(f);
  unsigned r = (x + 0x7fffu + ((x>>16)&1u)) >> 16;
  return (ushort_t)r;
}

// ---------------------------------------------------------------------------
// wl[i] = W_i @ attn_l_i, wr[i] = W_i @ attn_r_i ; bsum[j] = sum_i lam[i/2]*bias[i][j]
// ---------------------------------------------------------------------------
__global__ void wlr_kernel(const float* __restrict__ W, const float* __restrict__ al,
                           const float* __restrict__ ar, const float* __restrict__ bias,
                           const float* __restrict__ lam,
                           float* __restrict__ wl, float* __restrict__ wr,
                           float* __restrict__ bsum) {
  int i = blockIdx.x, j = threadIdx.x;         // 8 blocks x 128 threads
  const float* Wi  = W + ((size_t)i*128 + j)*128;
  const float* ali = al + i*128;
  const float* ari = ar + i*128;
  float sl = 0.f, sr = 0.f;
  for (int k = 0; k < 128; ++k) { float w = Wi[k]; sl += w*ali[k]; sr += w*ari[k]; }
  wl[i*128+j] = sl; wr[i*128+j] = sr;
  if (i == 0) {
    float b = 0.f;
    for (int t = 0; t < 8; ++t) b += lam[t>>1]*bias[t*128+j];
    bsum[j] = b;
  }
}

// ---------------------------------------------------------------------------
// Fragment-ready scaled weights:
// Wf[(((gat*4+kk)*8+f)*64+lane)*8 + i] = lam[gat/2] * W[gat][kk*32+(lane>>4)*8+i][f*16+(lane&15)]
// ---------------------------------------------------------------------------
__global__ __launch_bounds__(256) void wf_kernel(const float* __restrict__ W,
    const float* __restrict__ lam, ushort_t* __restrict__ Wf) {
  int tid = blockIdx.x*256 + threadIdx.x;       // 16384 threads
  if (tid >= 16384) return;
  int gat  = tid >> 11;
  int kk   = (tid >> 9) & 3;
  int f    = (tid >> 6) & 7;
  int lane = tid & 63;
  float c = lam[gat >> 1];
  int krow = kk*32 + (lane >> 4)*8;
  int col  = f*16 + (lane & 15);
  ushort_t v[8];
#pragma unroll
  for (int i = 0; i < 8; ++i)
    v[i] = f2bf(c * W[((size_t)gat*128 + krow + i)*128 + col]);
  ushort_t* o = Wf + (size_t)tid*8;
#pragma unroll
  for (int i = 0; i < 8; ++i) o[i] = v[i];
}

// ---------------------------------------------------------------------------
// Per-node attention scalars into att[n][16]: [0..7]=el_i, [8..15]=er_i
// ---------------------------------------------------------------------------
__global__ __launch_bounds__(256) void elr_kernel(const float* __restrict__ fs,
    const float* __restrict__ fd, const float* __restrict__ wl, const float* __restrict__ wr,
    float* __restrict__ att, int n) {
  int wid  = (blockIdx.x*256 + threadIdx.x) >> 6;
  int lane = threadIdx.x & 63;
  if (wid >= n) return;
  float2 s = *(const float2*)(fs + (size_t)wid*128 + lane*2);
  float2 d = *(const float2*)(fd + (size_t)wid*128 + lane*2);
#pragma unroll
  for (int i = 0; i < 8; ++i) {
    float2 wlv = *(const float2*)(wl + i*128 + lane*2);
    float2 wrv = *(const float2*)(wr + i*128 + lane*2);
    bool use_s = (i==0)||(i==1)||(i==4)||(i==5);
    float xx = use_s ? s.x : d.x;
    float xy = use_s ? s.y : d.y;
    float vl = xx*wlv.x + xy*wlv.y;
    float vr = d.x*wrv.x + d.y*wrv.y;
#pragma unroll
    for (int off = 32; off; off >>= 1) { vl += __shfl_xor(vl, off); vr += __shfl_xor(vr, off); }
    if (lane == 0) { att[(size_t)wid*16 + i] = vl; att[(size_t)wid*16 + 8 + i] = vr; }
  }
}

// ---------------------------------------------------------------------------
// bf16 feature table fb[n][2][128]: node's fs row then fd row, contiguous.
// ---------------------------------------------------------------------------
__global__ __launch_bounds__(256) void cvt_kernel(const float* __restrict__ fs,
    const float* __restrict__ fd, ushort_t* __restrict__ fb, int n) {
  int t = blockIdx.x*256 + threadIdx.x;         // handles 4 elements
  size_t idx = (size_t)t*4;
  if (idx >= (size_t)n*256) return;
  int node = (int)(idx >> 8);
  int half = (int)((idx >> 7) & 1);
  int k    = (int)(idx & 127);
  const float* src = (half ? fd : fs) + (size_t)node*128 + k;
  float4 v = *(const float4*)src;
  ushort4 u; u.x = f2bf(v.x); u.y = f2bf(v.y); u.z = f2bf(v.z); u.w = f2bf(v.w);
  *(ushort4*)(fb + idx) = u;
}

// ---------------------------------------------------------------------------
// CSR build over 4 graphs jointly (each has exactly e edges).
// g0: intra fwd, g1: inter fwd, g2: intra rev, g3: inter rev
// ---------------------------------------------------------------------------
__global__ __launch_bounds__(256) void hist_kernel(const int* __restrict__ ia_s,
    const int* __restrict__ ia_d, const int* __restrict__ ie_s, const int* __restrict__ ie_d,
    int* __restrict__ counts, int n, int e) {
  int t = blockIdx.x*256 + threadIdx.x;
  if (t >= 4*e) return;
  int g = t / e, idx = t - g*e;
  int d;
  if      (g == 0) d = ia_d[idx];
  else if (g == 1) d = ie_d[idx];
  else if (g == 2) d = ia_s[idx];
  else             d = ie_s[idx];
  atomicAdd(&counts[g*n + d], 1);
}

__global__ __launch_bounds__(256) void scan_local_kernel(const int* __restrict__ counts,
    int* __restrict__ rowptr, int* __restrict__ bsums, int total) {
  __shared__ int sh[256];
  int base = blockIdx.x*1024;
  int tid = threadIdx.x;
  int v[4]; int s = 0;
#pragma unroll
  for (int q = 0; q < 4; ++q) { int idx = base + tid*4 + q; int x = (idx < total) ? counts[idx] : 0; v[q] = x; s += x; }
  sh[tid] = s; __syncthreads();
  for (int off = 1; off < 256; off <<= 1) {
    int t2 = (tid >= off) ? sh[tid-off] : 0;
    __syncthreads();
    sh[tid] += t2;
    __syncthreads();
  }
  if (tid == 255) bsums[blockIdx.x] = sh[255];
  int run = sh[tid] - s;
#pragma unroll
  for (int q = 0; q < 4; ++q) { int idx = base + tid*4 + q; if (idx < total) rowptr[idx] = run; run += v[q]; }
}

__global__ void scan_bsums_kernel(int* __restrict__ bsums, int nb) {
  __shared__ int sh[1024];
  int tid = threadIdx.x;
  int v = (tid < nb) ? bsums[tid] : 0;
  sh[tid] = v; __syncthreads();
  for (int off = 1; off < 1024; off <<= 1) {
    int t2 = (tid >= off) ? sh[tid-off] : 0;
    __syncthreads();
    sh[tid] += t2;
    __syncthreads();
  }
  if (tid < nb) bsums[tid] = sh[tid] - v;   // exclusive
}

__global__ void scan_add_kernel(int* __restrict__ rowptr, const int* __restrict__ bsums,
                                int total, int grand) {
  int idx = blockIdx.x*blockDim.x + threadIdx.x;
  if (idx < total) rowptr[idx] += bsums[idx >> 10];
  if (idx == total) rowptr[total] = grand;
}

// cursor preloaded with rowptr values (d2d copy); one atomic + one store per edge
__global__ __launch_bounds__(256) void fill_kernel(const int* __restrict__ ia_s,
    const int* __restrict__ ia_d, const int* __restrict__ ie_s, const int* __restrict__ ie_d,
    int* __restrict__ cursor, int* __restrict__ col, int n, int e) {
  int t = blockIdx.x*256 + threadIdx.x;
  if (t >= 4*e) return;
  int g = t / e, idx = t - g*e;
  int d, s;
  if      (g == 0) { d = ia_d[idx]; s = ia_s[idx]; }
  else if (g == 1) { d = ie_d[idx]; s = ie_s[idx]; }
  else if (g == 2) { d = ia_s[idx]; s = ia_d[idx]; }
  else             { d = ie_s[idx]; s = ie_d[idx]; }
  int pos = atomicAdd(&cursor[g*n + d], 1);
  col[pos] = s;
}

// ---------------------------------------------------------------------------
// Single-pass softmax + aggregation (no max subtraction: |e| <~ 1 here, and
// softmax is shift-invariant so result matches ref to fp rounding).
// Wave per dst, 2 gats per graph. aggX layout [n][2][128] bf16.
// BF=1: gather bf16 fb[n][2][128]; BF=0: gather f32 fs/fd.
// ---------------------------------------------------------------------------
template<int BF>
__global__ __launch_bounds__(256) void agg_kernel(const float* __restrict__ fs,
    const float* __restrict__ fd, const ushort_t* __restrict__ fb,
    const float* __restrict__ att, const int* __restrict__ rowptr,
    const int* __restrict__ col, ushort_t* __restrict__ aggX,
    int g, int gatA, int gatB, int n) {
  int d    = (blockIdx.x*256 + threadIdx.x) >> 6;
  int lane = threadIdx.x & 63;
  if (d >= n) return;
  int row = rowptr[g*n + d], end = rowptr[g*n + d + 1];
  float aAx = 0.f, aAy = 0.f, aBx = 0.f, aBy = 0.f;
  if (end > row) {
    float erA = att[(size_t)d*16 + 8 + gatA];
    float erB = att[(size_t)d*16 + 8 + gatB];
    float dA = 0.f, dB = 0.f;
    for (int e2 = row; e2 < end; ++e2) {
      int s = col[e2];
      float elA = att[(size_t)s*16 + gatA];
      float elB = att[(size_t)s*16 + gatB];
      float ea = elA + erA; ea = (ea > 0.f) ? ea : 0.2f*ea;
      float eb = elB + erB; eb = (eb > 0.f) ? eb : 0.2f*eb;
      float pa = __expf(ea), pb = __expf(eb);
      dA += pa; dB += pb;
      if (BF) {
        ushort2 us = *(const ushort2*)(fb + (size_t)s*256 + lane*2);
        ushort2 ud = *(const ushort2*)(fb + (size_t)s*256 + 128 + lane*2);
        aAx += pa*bf2f(us.x); aAy += pa*bf2f(us.y);
        aBx += pb*bf2f(ud.x); aBy += pb*bf2f(ud.y);
      } else {
        float2 xs = *(const float2*)(fs + (size_t)s*128 + lane*2);
        float2 xd = *(const float2*)(fd + (size_t)s*128 + lane*2);
        aAx += pa*xs.x; aAy += pa*xs.y;
        aBx += pb*xd.x; aBy += pb*xd.y;
      }
    }
    float rA = 1.f/fmaxf(dA, 1e-9f), rB = 1.f/fmaxf(dB, 1e-9f);
    aAx *= rA; aAy *= rA; aBx *= rB; aBy *= rB;
  }
  ushort2 uA; uA.x = f2bf(aAx); uA.y = f2bf(aAy);
  ushort2 uB; uB.x = f2bf(aBx); uB.y = f2bf(aBy);
  *(ushort2*)(aggX + ((size_t)d*2 + 0)*128 + lane*2) = uA;
  *(ushort2*)(aggX + ((size_t)d*2 + 1)*128 + lane*2) = uB;
}

// ---------------------------------------------------------------------------
// out (+)= aggX[n x 256] @ Wf-combined[256 x 128]  via bf16 MFMA 16x16x32.
// Block: 4 waves x 16 rows = 64 rows, N=128 (8 frags), K=256 (8 ksteps).
// first pass adds residual 2*(sum lam)*fd + bsum; later passes accumulate out.
// ---------------------------------------------------------------------------
__global__ __launch_bounds__(256) void mfma_gemm_kernel(const ushort_t* __restrict__ A,
    const ushort_t* __restrict__ Wf, const float* __restrict__ lam,
    const float* __restrict__ fd, const float* __restrict__ bsum,
    float* __restrict__ out, int n, int gatA, int gatB, int first) {
  int t = threadIdx.x;
  int wave = t >> 6, lane = t & 63;
  int m0 = blockIdx.x*64 + wave*16;
  int lr = lane & 15, lg = lane >> 4;
  f32x4 acc[8];
#pragma unroll
  for (int f = 0; f < 8; ++f) { f32x4 z = {0.f,0.f,0.f,0.f}; acc[f] = z; }
  int arow = m0 + lr; if (arow >= n) arow = n - 1;
  const ushort_t* ap = A + (size_t)arow*256 + lg*8;
#pragma unroll
  for (int ks = 0; ks < 8; ++ks) {
    bf16x8 a = *reinterpret_cast<const bf16x8*>(ap + ks*32);
    int gat = (ks < 4) ? gatA : gatB;
    int kk  = ks & 3;
    const ushort_t* bp = Wf + ((size_t)(gat*4 + kk)*8*64 + lane)*8;
#pragma unroll
    for (int f = 0; f < 8; ++f) {
      bf16x8 b = *reinterpret_cast<const bf16x8*>(bp + (size_t)f*64*8);
      acc[f] = __builtin_amdgcn_mfma_f32_16x16x32_bf16(a, b, acc[f], 0, 0, 0);
    }
  }
  float rc = 2.f*(lam[0]+lam[1]+lam[2]+lam[3]);
#pragma unroll
  for (int f = 0; f < 8; ++f) {
#pragma unroll
    for (int r = 0; r < 4; ++r) {
      int gr = m0 + lg*4 + r;
      if (gr < n) {
        int gc = f*16 + lr;
        size_t o = (size_t)gr*128 + gc;
        float v = acc[f][r];
        if (first) v += rc*fd[o] + bsum[gc];
        else       v += out[o];
        out[o] = v;
      }
    }
  }
}

// ---------------------------------------------------------------------------
extern "C" void kernel_launch(void* const* d_in, const int* in_sizes, int n_in,
                              void* d_out, int out_size, void* d_ws, size_t ws_size,
                              hipStream_t stream) {
  const float* fs  = (const float*)d_in[0];
  const float* fd  = (const float*)d_in[1];
  const int* ia_s  = (const int*)d_in[2];
  const int* ia_d  = (const int*)d_in[3];
  const int* ie_s  = (const int*)d_in[4];
  const int* ie_d  = (const int*)d_in[5];
  const float* W   = (const float*)d_in[6];
  const float* al  = (const float*)d_in[7];
  const float* ar  = (const float*)d_in[8];
  const float* bias= (const float*)d_in[9];
  const float* lam = (const float*)d_in[10];
  int n = in_sizes[0] / 128;
  int e = in_sizes[2];
  float* out = (float*)d_out;

  char* ws = (char*)d_ws;
  size_t off = 0;
  auto alloc = [&](size_t bytes) -> char* { char* p = ws + off; off += (bytes + 255) & ~(size_t)255; return p; };
  float* wl      = (float*)alloc((size_t)8*128*4);
  float* wr      = (float*)alloc((size_t)8*128*4);
  float* bsum    = (float*)alloc(128*4);
  float* att     = (float*)alloc((size_t)n*16*4);
  int*   counts  = (int*)alloc((size_t)4*n*4);          // reused as cursor
  int*   rowptr  = (int*)alloc(((size_t)4*n + 1)*4);
  int*   bsums   = (int*)alloc(4096);
  int*   colv    = (int*)alloc((size_t)4*e*4);
  ushort_t* Wf   = (ushort_t*)alloc((size_t)8*128*128*2);
  ushort_t* aggX = (ushort_t*)alloc((size_t)n*256*2);
  size_t base_end = off;
  ushort_t* fb   = (ushort_t*)alloc((size_t)n*256*2);   // optional bf16 features
  bool use_bf = (off <= ws_size);
  (void)base_end; (void)n_in; (void)out_size;

  hipLaunchKernelGGL(wlr_kernel, dim3(8), dim3(128), 0, stream, W, al, ar, bias, lam, wl, wr, bsum);
  hipLaunchKernelGGL(wf_kernel, dim3(64), dim3(256), 0, stream, W, lam, Wf);
  hipLaunchKernelGGL(elr_kernel, dim3((n+3)/4), dim3(256), 0, stream, fs, fd, wl, wr, att, n);
  if (use_bf)
    hipLaunchKernelGGL(cvt_kernel, dim3((int)(((size_t)n*256/4 + 255)/256)), dim3(256), 0, stream, fs, fd, fb, n);

  hipMemsetAsync(counts, 0, (size_t)4*n*4, stream);
  hipLaunchKernelGGL(hist_kernel, dim3((4*e+255)/256), dim3(256), 0, stream,
                     ia_s, ia_d, ie_s, ie_d, counts, n, e);
  int total = 4*n;
  int nb = (total + 1023)/1024;
  hipLaunchKernelGGL(scan_local_kernel, dim3(nb), dim3(256), 0, stream, counts, rowptr, bsums, total);
  hipLaunchKernelGGL(scan_bsums_kernel, dim3(1), dim3(1024), 0, stream, bsums, nb);
  hipLaunchKernelGGL(scan_add_kernel, dim3((total+1+255)/256), dim3(256), 0, stream, rowptr, bsums, total, 4*e);
  hipMemcpyAsync(counts, rowptr, (size_t)4*n*4, hipMemcpyDeviceToDevice, stream);
  hipLaunchKernelGGL(fill_kernel, dim3((4*e+255)/256), dim3(256), 0, stream,
                     ia_s, ia_d, ie_s, ie_d, counts, colv, n, e);

  const int gA[4] = {0, 1, 4, 5};
  const int gB[4] = {2, 3, 6, 7};
  for (int g = 0; g < 4; ++g) {
    if (use_bf)
      hipLaunchKernelGGL(agg_kernel<1>, dim3((n+3)/4), dim3(256), 0, stream,
                         fs, fd, fb, att, rowptr, colv, aggX, g, gA[g], gB[g], n);
    else
      hipLaunchKernelGGL(agg_kernel<0>, dim3((n+3)/4), dim3(256), 0, stream,
                         fs, fd, fb, att, rowptr, colv, aggX, g, gA[g], gB[g], n);
    hipLaunchKernelGGL(mfma_gemm_kernel, dim3((n+63)/64), dim3(256), 0, stream,
                       aggX, Wf, lam, fd, bsum, out, n, gA[g], gB[g], (g==0) ? 1 : 0);
  }
}

// Round 4
// 1019.678 us; speedup vs baseline: 1.5550x; 1.0548x over previous
//
#include <hip/hip_runtime.h>
#include <hip/hip_bf16.h>

typedef unsigned short ushort_t;
typedef __bf16 bf16x8 __attribute__((ext_vector_type(8)));
typedef float f32x4 __attribute__((ext_vector_type(4)));

__device__ __forceinline__ float bf2f(ushort_t u){ return __uint_as_float(((unsigned)u)<<16); }
__device__ __forceinline__ ushort_t f2bf(float f){
  unsigned x = __float_as_uint(f);
  unsigned r = (x + 0x7fffu + ((x>>16)&1u)) >> 16;
  return (ushort_t)r;
}

// ---------------------------------------------------------------------------
// wl[i] = W_i @ attn_l_i, wr[i] = W_i @ attn_r_i ; bsum[j] = sum_i lam[i/2]*bias[i][j]
// ---------------------------------------------------------------------------
__global__ void wlr_kernel(const float* __restrict__ W, const float* __restrict__ al,
                           const float* __restrict__ ar, const float* __restrict__ bias,
                           const float* __restrict__ lam,
                           float* __restrict__ wl, float* __restrict__ wr,
                           float* __restrict__ bsum) {
  int i = blockIdx.x, j = threadIdx.x;         // 8 blocks x 128 threads
  const float* Wi  = W + ((size_t)i*128 + j)*128;
  const float* ali = al + i*128;
  const float* ari = ar + i*128;
  float sl = 0.f, sr = 0.f;
  for (int k = 0; k < 128; ++k) { float w = Wi[k]; sl += w*ali[k]; sr += w*ari[k]; }
  wl[i*128+j] = sl; wr[i*128+j] = sr;
  if (i == 0) {
    float b = 0.f;
    for (int t = 0; t < 8; ++t) b += lam[t>>1]*bias[t*128+j];
    bsum[j] = b;
  }
}

// ---------------------------------------------------------------------------
// Fragment-ready scaled weights (layout bench-verified in round 2):
// Wf[(((gat*4+kk)*8+f)*64+lane)*8 + i] = lam[gat/2]*W[gat][kk*32+(lane>>4)*8+i][f*16+(lane&15)]
// ---------------------------------------------------------------------------
__global__ __launch_bounds__(256) void wf_kernel(const float* __restrict__ W,
    const float* __restrict__ lam, ushort_t* __restrict__ Wf) {
  int tid = blockIdx.x*256 + threadIdx.x;       // 16384 threads
  if (tid >= 16384) return;
  int gat  = tid >> 11;
  int kk   = (tid >> 9) & 3;
  int f    = (tid >> 6) & 7;
  int lane = tid & 63;
  float c = lam[gat >> 1];
  int krow = kk*32 + (lane >> 4)*8;
  int col  = f*16 + (lane & 15);
  ushort_t v[8];
#pragma unroll
  for (int i = 0; i < 8; ++i)
    v[i] = f2bf(c * W[((size_t)gat*128 + krow + i)*128 + col]);
  ushort_t* o = Wf + (size_t)tid*8;
#pragma unroll
  for (int i = 0; i < 8; ++i) o[i] = v[i];
}

// ---------------------------------------------------------------------------
// prep: fused attention scalars + bf16 feature table.
// att[n][16]: [0..7]=el_i, [8..15]=er_i.  fb[n][256]: fs row then fd row.
// ---------------------------------------------------------------------------
__global__ __launch_bounds__(256) void prep_kernel(const float* __restrict__ fs,
    const float* __restrict__ fd, const float* __restrict__ wl, const float* __restrict__ wr,
    float* __restrict__ att, ushort_t* __restrict__ fb, int n) {
  int wid  = (blockIdx.x*256 + threadIdx.x) >> 6;
  int lane = threadIdx.x & 63;
  if (wid >= n) return;
  float2 s = *(const float2*)(fs + (size_t)wid*128 + lane*2);
  float2 d = *(const float2*)(fd + (size_t)wid*128 + lane*2);
  ushort2 us; us.x = f2bf(s.x); us.y = f2bf(s.y);
  ushort2 ud; ud.x = f2bf(d.x); ud.y = f2bf(d.y);
  *(ushort2*)(fb + (size_t)wid*256 + lane*2) = us;
  *(ushort2*)(fb + (size_t)wid*256 + 128 + lane*2) = ud;
#pragma unroll
  for (int i = 0; i < 8; ++i) {
    float2 wlv = *(const float2*)(wl + i*128 + lane*2);
    float2 wrv = *(const float2*)(wr + i*128 + lane*2);
    bool use_s = (i==0)||(i==1)||(i==4)||(i==5);
    float xx = use_s ? s.x : d.x;
    float xy = use_s ? s.y : d.y;
    float vl = xx*wlv.x + xy*wlv.y;
    float vr = d.x*wrv.x + d.y*wrv.y;
#pragma unroll
    for (int off = 32; off; off >>= 1) { vl += __shfl_xor(vl, off); vr += __shfl_xor(vr, off); }
    if (lane == 0) { att[(size_t)wid*16 + i] = vl; att[(size_t)wid*16 + 8 + i] = vr; }
  }
}

// ---------------------------------------------------------------------------
// CSR build, XCD-partitioned: blockIdx%8 -> dst range; each group scans all
// edges and filters, so atomics + col stores stay XCD-local (L2 coalescing).
// g0: intra fwd, g1: inter fwd, g2: intra rev, g3: inter rev
// ---------------------------------------------------------------------------
__global__ __launch_bounds__(256) void hist_kernel(const int* __restrict__ ia_s,
    const int* __restrict__ ia_d, const int* __restrict__ ie_s, const int* __restrict__ ie_d,
    int* __restrict__ counts, int n, int e, int n8) {
  int x = blockIdx.x & 7;
  int lo = x*n8, hi = lo + n8; if (hi > n) hi = n;
  int tid = (blockIdx.x >> 3)*256 + threadIdx.x;
  int stride = (gridDim.x >> 3) << 8;
#pragma unroll
  for (int g = 0; g < 4; ++g) {
    const int* dp = (g==0) ? ia_d : (g==1) ? ie_d : (g==2) ? ia_s : ie_s;
    int bo = g*n;
    for (int i = tid; i < e; i += stride) {
      int d = dp[i];
      if (d >= lo && d < hi) atomicAdd(&counts[bo + d], 1);
    }
  }
}

__global__ __launch_bounds__(256) void scan_local_kernel(const int* __restrict__ counts,
    int* __restrict__ rowptr, int* __restrict__ bsums, int total) {
  __shared__ int sh[256];
  int base = blockIdx.x*1024;
  int tid = threadIdx.x;
  int v[4]; int s = 0;
#pragma unroll
  for (int q = 0; q < 4; ++q) { int idx = base + tid*4 + q; int x = (idx < total) ? counts[idx] : 0; v[q] = x; s += x; }
  sh[tid] = s; __syncthreads();
  for (int off = 1; off < 256; off <<= 1) {
    int t2 = (tid >= off) ? sh[tid-off] : 0;
    __syncthreads();
    sh[tid] += t2;
    __syncthreads();
  }
  if (tid == 255) bsums[blockIdx.x] = sh[255];
  int run = sh[tid] - s;
#pragma unroll
  for (int q = 0; q < 4; ++q) { int idx = base + tid*4 + q; if (idx < total) rowptr[idx] = run; run += v[q]; }
}

__global__ void scan_bsums_kernel(int* __restrict__ bsums, int nb) {
  __shared__ int sh[1024];
  int tid = threadIdx.x;
  int v = (tid < nb) ? bsums[tid] : 0;
  sh[tid] = v; __syncthreads();
  for (int off = 1; off < 1024; off <<= 1) {
    int t2 = (tid >= off) ? sh[tid-off] : 0;
    __syncthreads();
    sh[tid] += t2;
    __syncthreads();
  }
  if (tid < nb) bsums[tid] = sh[tid] - v;   // exclusive
}

__global__ void scan_add_kernel(int* __restrict__ rowptr, const int* __restrict__ bsums,
                                int total, int grand) {
  int idx = blockIdx.x*blockDim.x + threadIdx.x;
  if (idx < total) rowptr[idx] += bsums[idx >> 10];
  if (idx == total) rowptr[total] = grand;
}

// cursor preloaded with rowptr (d2d copy). XCD-partitioned like hist.
__global__ __launch_bounds__(256) void fill_kernel(const int* __restrict__ ia_s,
    const int* __restrict__ ia_d, const int* __restrict__ ie_s, const int* __restrict__ ie_d,
    int* __restrict__ cursor, int* __restrict__ col, int n, int e, int n8) {
  int x = blockIdx.x & 7;
  int lo = x*n8, hi = lo + n8; if (hi > n) hi = n;
  int tid = (blockIdx.x >> 3)*256 + threadIdx.x;
  int stride = (gridDim.x >> 3) << 8;
#pragma unroll
  for (int g = 0; g < 4; ++g) {
    const int* dp = (g==0) ? ia_d : (g==1) ? ie_d : (g==2) ? ia_s : ie_s;
    const int* sp = (g==0) ? ia_s : (g==1) ? ie_s : (g==2) ? ia_d : ie_d;
    int bo = g*n;
    for (int i = tid; i < e; i += stride) {
      int d = dp[i];
      if (d >= lo && d < hi) {
        int s = sp[i];
        int pos = atomicAdd(&cursor[bo + d], 1);
        col[pos] = s;
      }
    }
  }
}

// ---------------------------------------------------------------------------
// Fused aggregation + GEMM + epilogue. Block = 16 dsts, 4 waves.
// Phase 1: wave w aggregates graph w (gats gA[w]=w<2?w:w+2, gB=gA+2) for the
//   16 dsts into LDS A-tile [16][1024] bf16 (K-chunk w*256, XOR-swizzled).
// Phase 2: wave w MFMAs K=1024 for output cols [w*32, w*32+32).
// Epilogue: out = C + 2*sum(lam)*fd + bsum  (written exactly once).
// ---------------------------------------------------------------------------
__global__ __launch_bounds__(256) void fused_kernel(const ushort_t* __restrict__ fb,
    const float* __restrict__ att, const int* __restrict__ rowptr,
    const int* __restrict__ col, const ushort_t* __restrict__ Wf,
    const float* __restrict__ lam, const float* __restrict__ fd,
    const float* __restrict__ bsum, float* __restrict__ out, int n) {
  __shared__ ushort_t As[16*1024];
  int t = threadIdx.x, w = t >> 6, lane = t & 63;
  int base = blockIdx.x*16;
  int gatA = (w < 2) ? w : w + 2;
  int gatB = gatA + 2;

  // ---- phase 1: aggregation (graph w), dsts base..base+15
  for (int i = 0; i < 16; ++i) {
    int d = base + i; if (d >= n) d = n - 1;
    int row = rowptr[(size_t)w*n + d], end = rowptr[(size_t)w*n + d + 1];
    float a0 = 0.f, a1 = 0.f, a2 = 0.f, a3 = 0.f;
    if (end > row) {
      float erA = att[(size_t)d*16 + 8 + gatA];
      float erB = att[(size_t)d*16 + 8 + gatB];
      float dA = 0.f, dB = 0.f;
      for (int e2 = row; e2 < end; ++e2) {
        int s = col[e2];
        float ea = att[(size_t)s*16 + gatA] + erA; ea = (ea > 0.f) ? ea : 0.2f*ea;
        float eb = att[(size_t)s*16 + gatB] + erB; eb = (eb > 0.f) ? eb : 0.2f*eb;
        float pa = __expf(ea), pb = __expf(eb);
        dA += pa; dB += pb;
        ushort4 u = *(const ushort4*)(fb + (size_t)s*256 + lane*4);
        float wgt = (lane < 32) ? pa : pb;
        a0 += wgt*bf2f(u.x); a1 += wgt*bf2f(u.y);
        a2 += wgt*bf2f(u.z); a3 += wgt*bf2f(u.w);
      }
      float r = 1.f/fmaxf((lane < 32) ? dA : dB, 1e-9f);
      a0 *= r; a1 *= r; a2 *= r; a3 *= r;
    }
    ushort4 o; o.x = f2bf(a0); o.y = f2bf(a1); o.z = f2bf(a2); o.w = f2bf(a3);
    int k = w*256 + lane*4;
    int idx = i*1024 + (k ^ ((i & 7) << 3));
    *(ushort4*)(As + idx) = o;
  }
  __syncthreads();

  // ---- phase 2: MFMA over K=1024, wave w owns cols [w*32, w*32+32)
  int lr = lane & 15, lg = lane >> 4;
  f32x4 c0 = {0.f,0.f,0.f,0.f}, c1 = {0.f,0.f,0.f,0.f};
#pragma unroll
  for (int ks = 0; ks < 32; ++ks) {
    int kc = ks*32 + lg*8;
    int idx = lr*1024 + (kc ^ ((lr & 7) << 3));
    bf16x8 a = *reinterpret_cast<const bf16x8*>(As + idx);
    int wp = ks >> 3, sub = ks & 7;
    int gat = ((sub >= 4) ? 2 : 0) + ((wp < 2) ? wp : wp + 2);
    int kk = sub & 3;
    const ushort_t* bp = Wf + (((size_t)(gat*4 + kk)*8 + w*2)*64 + lane)*8;
    bf16x8 b0 = *reinterpret_cast<const bf16x8*>(bp);
    bf16x8 b1 = *reinterpret_cast<const bf16x8*>(bp + 64*8);
    c0 = __builtin_amdgcn_mfma_f32_16x16x32_bf16(a, b0, c0, 0, 0, 0);
    c1 = __builtin_amdgcn_mfma_f32_16x16x32_bf16(a, b1, c1, 0, 0, 0);
  }
  float rc = 2.f*(lam[0] + lam[1] + lam[2] + lam[3]);
#pragma unroll
  for (int q = 0; q < 2; ++q) {
    f32x4 c = q ? c1 : c0;
    int gc = (w*2 + q)*16 + lr;
#pragma unroll
    for (int r2 = 0; r2 < 4; ++r2) {
      int gr = base + lg*4 + r2;
      if (gr < n) {
        size_t o = (size_t)gr*128 + gc;
        out[o] = c[r2] + rc*fd[o] + bsum[gc];
      }
    }
  }
}

// ---------------------------------------------------------------------------
extern "C" void kernel_launch(void* const* d_in, const int* in_sizes, int n_in,
                              void* d_out, int out_size, void* d_ws, size_t ws_size,
                              hipStream_t stream) {
  const float* fs  = (const float*)d_in[0];
  const float* fd  = (const float*)d_in[1];
  const int* ia_s  = (const int*)d_in[2];
  const int* ia_d  = (const int*)d_in[3];
  const int* ie_s  = (const int*)d_in[4];
  const int* ie_d  = (const int*)d_in[5];
  const float* W   = (const float*)d_in[6];
  const float* al  = (const float*)d_in[7];
  const float* ar  = (const float*)d_in[8];
  const float* bias= (const float*)d_in[9];
  const float* lam = (const float*)d_in[10];
  int n = in_sizes[0] / 128;
  int e = in_sizes[2];
  float* out = (float*)d_out;

  char* ws = (char*)d_ws;
  size_t off = 0;
  auto alloc = [&](size_t bytes) -> char* { char* p = ws + off; off += (bytes + 255) & ~(size_t)255; return p; };
  float* wl      = (float*)alloc((size_t)8*128*4);
  float* wr      = (float*)alloc((size_t)8*128*4);
  float* bsum    = (float*)alloc(128*4);
  float* att     = (float*)alloc((size_t)n*16*4);
  int*   counts  = (int*)alloc((size_t)4*n*4);          // reused as cursor
  int*   rowptr  = (int*)alloc(((size_t)4*n + 1)*4);
  int*   bsums   = (int*)alloc(4096);
  int*   colv    = (int*)alloc((size_t)4*e*4);
  ushort_t* Wf   = (ushort_t*)alloc((size_t)8*128*128*2);
  ushort_t* fb   = (ushort_t*)alloc((size_t)n*256*2);
  (void)ws_size; (void)n_in; (void)out_size;

  int n8 = (n + 7)/8;

  hipLaunchKernelGGL(wlr_kernel, dim3(8), dim3(128), 0, stream, W, al, ar, bias, lam, wl, wr, bsum);
  hipLaunchKernelGGL(wf_kernel, dim3(64), dim3(256), 0, stream, W, lam, Wf);
  hipLaunchKernelGGL(prep_kernel, dim3((n+3)/4), dim3(256), 0, stream, fs, fd, wl, wr, att, fb, n);

  hipMemsetAsync(counts, 0, (size_t)4*n*4, stream);
  hipLaunchKernelGGL(hist_kernel, dim3(8*160), dim3(256), 0, stream,
                     ia_s, ia_d, ie_s, ie_d, counts, n, e, n8);
  int total = 4*n;
  int nb = (total + 1023)/1024;
  hipLaunchKernelGGL(scan_local_kernel, dim3(nb), dim3(256), 0, stream, counts, rowptr, bsums, total);
  hipLaunchKernelGGL(scan_bsums_kernel, dim3(1), dim3(1024), 0, stream, bsums, nb);
  hipLaunchKernelGGL(scan_add_kernel, dim3((total+1+255)/256), dim3(256), 0, stream, rowptr, bsums, total, 4*e);
  hipMemcpyAsync(counts, rowptr, (size_t)4*n*4, hipMemcpyDeviceToDevice, stream);
  hipLaunchKernelGGL(fill_kernel, dim3(8*160), dim3(256), 0, stream,
                     ia_s, ia_d, ie_s, ie_d, counts, colv, n, e, n8);

  hipLaunchKernelGGL(fused_kernel, dim3((n+15)/16), dim3(256), 0, stream,
                     fb, att, rowptr, colv, Wf, lam, fd, bsum, out, n);
}

// Round 5
// 719.122 us; speedup vs baseline: 2.2049x; 1.4179x over previous
//
#include <hip/hip_runtime.h>
#include <hip/hip_bf16.h>

typedef unsigned short ushort_t;
typedef __bf16 bf16x8 __attribute__((ext_vector_type(8)));
typedef ushort_t u16x8 __attribute__((ext_vector_type(8)));
typedef float f32x4 __attribute__((ext_vector_type(4)));

__device__ __forceinline__ float bf2f(ushort_t u){ return __uint_as_float(((unsigned)u)<<16); }
__device__ __forceinline__ ushort_t f2bf(float f){
  unsigned x = __float_as_uint(f);
  unsigned r = (x + 0x7fffu + ((x>>16)&1u)) >> 16;
  return (ushort_t)r;
}

// ---------------------------------------------------------------------------
// wl[i] = W_i @ attn_l_i, wr[i] = W_i @ attn_r_i ; bsum[j] = sum_i lam[i/2]*bias[i][j]
// ---------------------------------------------------------------------------
__global__ void wlr_kernel(const float* __restrict__ W, const float* __restrict__ al,
                           const float* __restrict__ ar, const float* __restrict__ bias,
                           const float* __restrict__ lam,
                           float* __restrict__ wl, float* __restrict__ wr,
                           float* __restrict__ bsum) {
  int i = blockIdx.x, j = threadIdx.x;         // 8 blocks x 128 threads
  const float* Wi  = W + ((size_t)i*128 + j)*128;
  const float* ali = al + i*128;
  const float* ari = ar + i*128;
  float sl = 0.f, sr = 0.f;
  for (int k = 0; k < 128; ++k) { float w = Wi[k]; sl += w*ali[k]; sr += w*ari[k]; }
  wl[i*128+j] = sl; wr[i*128+j] = sr;
  if (i == 0) {
    float b = 0.f;
    for (int t = 0; t < 8; ++t) b += lam[t>>1]*bias[t*128+j];
    bsum[j] = b;
  }
}

// ---------------------------------------------------------------------------
// Fragment-ready scaled weights (layout bench-verified in round 2):
// Wf[(((gat*4+kk)*8+f)*64+lane)*8 + i] = lam[gat/2]*W[gat][kk*32+(lane>>4)*8+i][f*16+(lane&15)]
// ---------------------------------------------------------------------------
__global__ __launch_bounds__(256) void wf_kernel(const float* __restrict__ W,
    const float* __restrict__ lam, ushort_t* __restrict__ Wf) {
  int tid = blockIdx.x*256 + threadIdx.x;       // 16384 threads
  if (tid >= 16384) return;
  int gat  = tid >> 11;
  int kk   = (tid >> 9) & 3;
  int f    = (tid >> 6) & 7;
  int lane = tid & 63;
  float c = lam[gat >> 1];
  int krow = kk*32 + (lane >> 4)*8;
  int col  = f*16 + (lane & 15);
  ushort_t v[8];
#pragma unroll
  for (int i = 0; i < 8; ++i)
    v[i] = f2bf(c * W[((size_t)gat*128 + krow + i)*128 + col]);
  ushort_t* o = Wf + (size_t)tid*8;
#pragma unroll
  for (int i = 0; i < 8; ++i) o[i] = v[i];
}

// ---------------------------------------------------------------------------
// prep: fused attention scalars + bf16 feature table.
// att[n][16]: [0..7]=el_i, [8..15]=er_i.  fb[n][256]: fs row then fd row.
// ---------------------------------------------------------------------------
__global__ __launch_bounds__(256) void prep_kernel(const float* __restrict__ fs,
    const float* __restrict__ fd, const float* __restrict__ wl, const float* __restrict__ wr,
    float* __restrict__ att, ushort_t* __restrict__ fb, int n) {
  int wid  = (blockIdx.x*256 + threadIdx.x) >> 6;
  int lane = threadIdx.x & 63;
  if (wid >= n) return;
  float2 s = *(const float2*)(fs + (size_t)wid*128 + lane*2);
  float2 d = *(const float2*)(fd + (size_t)wid*128 + lane*2);
  ushort2 us; us.x = f2bf(s.x); us.y = f2bf(s.y);
  ushort2 ud; ud.x = f2bf(d.x); ud.y = f2bf(d.y);
  *(ushort2*)(fb + (size_t)wid*256 + lane*2) = us;
  *(ushort2*)(fb + (size_t)wid*256 + 128 + lane*2) = ud;
#pragma unroll
  for (int i = 0; i < 8; ++i) {
    float2 wlv = *(const float2*)(wl + i*128 + lane*2);
    float2 wrv = *(const float2*)(wr + i*128 + lane*2);
    bool use_s = (i==0)||(i==1)||(i==4)||(i==5);
    float xx = use_s ? s.x : d.x;
    float xy = use_s ? s.y : d.y;
    float vl = xx*wlv.x + xy*wlv.y;
    float vr = d.x*wrv.x + d.y*wrv.y;
#pragma unroll
    for (int off = 32; off; off >>= 1) { vl += __shfl_xor(vl, off); vr += __shfl_xor(vr, off); }
    if (lane == 0) { att[(size_t)wid*16 + i] = vl; att[(size_t)wid*16 + 8 + i] = vr; }
  }
}

// ---------------------------------------------------------------------------
// CSR build, XCD-partitioned (blockIdx%8 -> dst range).
// g0: intra fwd, g1: inter fwd, g2: intra rev, g3: inter rev
// ---------------------------------------------------------------------------
__global__ __launch_bounds__(256) void hist_kernel(const int* __restrict__ ia_s,
    const int* __restrict__ ia_d, const int* __restrict__ ie_s, const int* __restrict__ ie_d,
    int* __restrict__ counts, int n, int e, int n8) {
  int x = blockIdx.x & 7;
  int lo = x*n8, hi = lo + n8; if (hi > n) hi = n;
  int tid = (blockIdx.x >> 3)*256 + threadIdx.x;
  int stride = (gridDim.x >> 3) << 8;
#pragma unroll
  for (int g = 0; g < 4; ++g) {
    const int* dp = (g==0) ? ia_d : (g==1) ? ie_d : (g==2) ? ia_s : ie_s;
    int bo = g*n;
    for (int i = tid; i < e; i += stride) {
      int d = dp[i];
      if (d >= lo && d < hi) atomicAdd(&counts[bo + d], 1);
    }
  }
}

__global__ __launch_bounds__(256) void scan_local_kernel(const int* __restrict__ counts,
    int* __restrict__ rowptr, int* __restrict__ bsums, int total) {
  __shared__ int sh[256];
  int base = blockIdx.x*1024;
  int tid = threadIdx.x;
  int v[4]; int s = 0;
#pragma unroll
  for (int q = 0; q < 4; ++q) { int idx = base + tid*4 + q; int x = (idx < total) ? counts[idx] : 0; v[q] = x; s += x; }
  sh[tid] = s; __syncthreads();
  for (int off = 1; off < 256; off <<= 1) {
    int t2 = (tid >= off) ? sh[tid-off] : 0;
    __syncthreads();
    sh[tid] += t2;
    __syncthreads();
  }
  if (tid == 255) bsums[blockIdx.x] = sh[255];
  int run = sh[tid] - s;
#pragma unroll
  for (int q = 0; q < 4; ++q) { int idx = base + tid*4 + q; if (idx < total) rowptr[idx] = run; run += v[q]; }
}

__global__ void scan_bsums_kernel(int* __restrict__ bsums, int nb) {
  __shared__ int sh[1024];
  int tid = threadIdx.x;
  int v = (tid < nb) ? bsums[tid] : 0;
  sh[tid] = v; __syncthreads();
  for (int off = 1; off < 1024; off <<= 1) {
    int t2 = (tid >= off) ? sh[tid-off] : 0;
    __syncthreads();
    sh[tid] += t2;
    __syncthreads();
  }
  if (tid < nb) bsums[tid] = sh[tid] - v;   // exclusive
}

__global__ void scan_add_kernel(int* __restrict__ rowptr, const int* __restrict__ bsums,
                                int total, int grand) {
  int idx = blockIdx.x*blockDim.x + threadIdx.x;
  if (idx < total) rowptr[idx] += bsums[idx >> 10];
  if (idx == total) rowptr[total] = grand;
}

// cursor preloaded with rowptr (d2d copy). XCD-partitioned like hist.
__global__ __launch_bounds__(256) void fill_kernel(const int* __restrict__ ia_s,
    const int* __restrict__ ia_d, const int* __restrict__ ie_s, const int* __restrict__ ie_d,
    int* __restrict__ cursor, int* __restrict__ col, int n, int e, int n8) {
  int x = blockIdx.x & 7;
  int lo = x*n8, hi = lo + n8; if (hi > n) hi = n;
  int tid = (blockIdx.x >> 3)*256 + threadIdx.x;
  int stride = (gridDim.x >> 3) << 8;
#pragma unroll
  for (int g = 0; g < 4; ++g) {
    const int* dp = (g==0) ? ia_d : (g==1) ? ie_d : (g==2) ? ia_s : ie_s;
    const int* sp = (g==0) ? ia_s : (g==1) ? ie_s : (g==2) ? ia_d : ie_d;
    int bo = g*n;
    for (int i = tid; i < e; i += stride) {
      int d = dp[i];
      if (d >= lo && d < hi) {
        int s = sp[i];
        int pos = atomicAdd(&cursor[bo + d], 1);
        col[pos] = s;
      }
    }
  }
}

// ---------------------------------------------------------------------------
// Fused aggregation + GEMM + epilogue. Block = 16 dsts, 8 waves (512 thr).
// Agg: wave w -> graph g=w>>1, dst-subset w&1 (8 dsts). Within a wave, lanes
//   split 32|32 into two edge slots; each 32-lane group loads the full 512B
//   fb row (ushort8/lane), lane (l&31) covers features [l*8,l*8+8):
//   l<16 -> fs half, weighted by pa (gatA); l>=16 -> fd half, pb (gatB).
//   One exp per lane; den + acc merged across halves via shfl_xor(32).
// MFMA: wave w owns col-frag f=w (16 cols), K=1024 over LDS A-tile
//   [16][1024] bf16 XOR-swizzled ((row&7)<<3 on 8-ushort blocks).
// Epilogue: out = C + 2*sum(lam)*fd + bsum  (written exactly once).
// ---------------------------------------------------------------------------
__global__ __launch_bounds__(512) void fused_kernel(const ushort_t* __restrict__ fb,
    const float* __restrict__ att, const int* __restrict__ rowptr,
    const int* __restrict__ col, const ushort_t* __restrict__ Wf,
    const float* __restrict__ lam, const float* __restrict__ fd,
    const float* __restrict__ bsum, float* __restrict__ out, int n) {
  __shared__ ushort_t As[16*1024];
  int t = threadIdx.x, w = t >> 6, lane = t & 63;
  int base = blockIdx.x*16;
  int g = w >> 1;
  int gatA = (g < 2) ? g : g + 2;
  int half = lane >> 5;          // which edge of the pair
  int l    = lane & 31;          // feature-slot within an edge group
  int typ  = (l >> 4) & 1;       // 0: fs/pa(gatA), 1: fd/pb(gatB)
  int gat  = gatA + 2*typ;

  // ---- phase 1: aggregation (graph g), 8 dsts per wave
  for (int i = 0; i < 8; ++i) {
    int di = (w & 1)*8 + i;
    int d = base + di; if (d >= n) d = n - 1;
    int row = rowptr[(size_t)g*n + d], end = rowptr[(size_t)g*n + d + 1];
    float er_ = att[(size_t)d*16 + 8 + gat];
    float acc0=0.f,acc1=0.f,acc2=0.f,acc3=0.f,acc4=0.f,acc5=0.f,acc6=0.f,acc7=0.f;
    float den = 0.f;
    for (int e2 = row + half; e2 < end; e2 += 2) {
      int s = col[e2];
      float ev = att[(size_t)s*16 + gat] + er_;
      ev = (ev > 0.f) ? ev : 0.2f*ev;
      float p = __expf(ev);
      den += p;
      u16x8 u = *reinterpret_cast<const u16x8*>(fb + (size_t)s*256 + l*8);
      acc0 += p*bf2f(u[0]); acc1 += p*bf2f(u[1]);
      acc2 += p*bf2f(u[2]); acc3 += p*bf2f(u[3]);
      acc4 += p*bf2f(u[4]); acc5 += p*bf2f(u[5]);
      acc6 += p*bf2f(u[6]); acc7 += p*bf2f(u[7]);
    }
    // merge the two edge-halves (same feature slice, same weight type)
    den  += __shfl_xor(den, 32);
    acc0 += __shfl_xor(acc0, 32); acc1 += __shfl_xor(acc1, 32);
    acc2 += __shfl_xor(acc2, 32); acc3 += __shfl_xor(acc3, 32);
    acc4 += __shfl_xor(acc4, 32); acc5 += __shfl_xor(acc5, 32);
    acc6 += __shfl_xor(acc6, 32); acc7 += __shfl_xor(acc7, 32);
    if (half == 0) {
      float r = 1.f/fmaxf(den, 1e-9f);
      u16x8 o;
      o[0]=f2bf(acc0*r); o[1]=f2bf(acc1*r); o[2]=f2bf(acc2*r); o[3]=f2bf(acc3*r);
      o[4]=f2bf(acc4*r); o[5]=f2bf(acc5*r); o[6]=f2bf(acc6*r); o[7]=f2bf(acc7*r);
      int k = g*256 + l*8;
      int idx = di*1024 + (k ^ ((di & 7) << 3));
      *reinterpret_cast<u16x8*>(As + idx) = o;
    }
  }
  __syncthreads();

  // ---- phase 2: MFMA over K=1024, wave w owns col-frag f=w
  int lr = lane & 15, lg = lane >> 4;
  f32x4 c0 = {0.f,0.f,0.f,0.f};
#pragma unroll
  for (int ks = 0; ks < 32; ++ks) {
    int kc = ks*32 + lg*8;
    int idx = lr*1024 + (kc ^ ((lr & 7) << 3));
    bf16x8 a = *reinterpret_cast<const bf16x8*>(As + idx);
    int wp = ks >> 3, sub = ks & 7;
    int gg = ((sub >= 4) ? 2 : 0) + ((wp < 2) ? wp : wp + 2);
    int kk = sub & 3;
    const ushort_t* bp = Wf + (((size_t)(gg*4 + kk)*8 + w)*64 + lane)*8;
    bf16x8 b0 = *reinterpret_cast<const bf16x8*>(bp);
    c0 = __builtin_amdgcn_mfma_f32_16x16x32_bf16(a, b0, c0, 0, 0, 0);
  }
  float rc = 2.f*(lam[0] + lam[1] + lam[2] + lam[3]);
  int gc = w*16 + lr;
#pragma unroll
  for (int r2 = 0; r2 < 4; ++r2) {
    int gr = base + lg*4 + r2;
    if (gr < n) {
      size_t o = (size_t)gr*128 + gc;
      out[o] = c0[r2] + rc*fd[o] + bsum[gc];
    }
  }
}

// ---------------------------------------------------------------------------
extern "C" void kernel_launch(void* const* d_in, const int* in_sizes, int n_in,
                              void* d_out, int out_size, void* d_ws, size_t ws_size,
                              hipStream_t stream) {
  const float* fs  = (const float*)d_in[0];
  const float* fd  = (const float*)d_in[1];
  const int* ia_s  = (const int*)d_in[2];
  const int* ia_d  = (const int*)d_in[3];
  const int* ie_s  = (const int*)d_in[4];
  const int* ie_d  = (const int*)d_in[5];
  const float* W   = (const float*)d_in[6];
  const float* al  = (const float*)d_in[7];
  const float* ar  = (const float*)d_in[8];
  const float* bias= (const float*)d_in[9];
  const float* lam = (const float*)d_in[10];
  int n = in_sizes[0] / 128;
  int e = in_sizes[2];
  float* out = (float*)d_out;

  char* ws = (char*)d_ws;
  size_t off = 0;
  auto alloc = [&](size_t bytes) -> char* { char* p = ws + off; off += (bytes + 255) & ~(size_t)255; return p; };
  float* wl      = (float*)alloc((size_t)8*128*4);
  float* wr      = (float*)alloc((size_t)8*128*4);
  float* bsum    = (float*)alloc(128*4);
  float* att     = (float*)alloc((size_t)n*16*4);
  int*   counts  = (int*)alloc((size_t)4*n*4);          // reused as cursor
  int*   rowptr  = (int*)alloc(((size_t)4*n + 1)*4);
  int*   bsums   = (int*)alloc(4096);
  int*   colv    = (int*)alloc((size_t)4*e*4);
  ushort_t* Wf   = (ushort_t*)alloc((size_t)8*128*128*2);
  ushort_t* fb   = (ushort_t*)alloc((size_t)n*256*2);
  (void)ws_size; (void)n_in; (void)out_size;

  int n8 = (n + 7)/8;

  hipLaunchKernelGGL(wlr_kernel, dim3(8), dim3(128), 0, stream, W, al, ar, bias, lam, wl, wr, bsum);
  hipLaunchKernelGGL(wf_kernel, dim3(64), dim3(256), 0, stream, W, lam, Wf);
  hipLaunchKernelGGL(prep_kernel, dim3((n+3)/4), dim3(256), 0, stream, fs, fd, wl, wr, att, fb, n);

  hipMemsetAsync(counts, 0, (size_t)4*n*4, stream);
  hipLaunchKernelGGL(hist_kernel, dim3(8*160), dim3(256), 0, stream,
                     ia_s, ia_d, ie_s, ie_d, counts, n, e, n8);
  int total = 4*n;
  int nb = (total + 1023)/1024;
  hipLaunchKernelGGL(scan_local_kernel, dim3(nb), dim3(256), 0, stream, counts, rowptr, bsums, total);
  hipLaunchKernelGGL(scan_bsums_kernel, dim3(1), dim3(1024), 0, stream, bsums, nb);
  hipLaunchKernelGGL(scan_add_kernel, dim3((total+1+255)/256), dim3(256), 0, stream, rowptr, bsums, total, 4*e);
  hipMemcpyAsync(counts, rowptr, (size_t)4*n*4, hipMemcpyDeviceToDevice, stream);
  hipLaunchKernelGGL(fill_kernel, dim3(8*160), dim3(256), 0, stream,
                     ia_s, ia_d, ie_s, ie_d, counts, colv, n, e, n8);

  hipLaunchKernelGGL(fused_kernel, dim3((n+15)/16), dim3(512), 0, stream,
                     fb, att, rowptr, colv, Wf, lam, fd, bsum, out, n);
}

// Round 6
// 710.323 us; speedup vs baseline: 2.2322x; 1.0124x over previous
//
#include <hip/hip_runtime.h>
#include <hip/hip_bf16.h>

typedef unsigned short ushort_t;
typedef __bf16 bf16x8 __attribute__((ext_vector_type(8)));
typedef ushort_t u16x8 __attribute__((ext_vector_type(8)));
typedef unsigned int u32x4 __attribute__((ext_vector_type(4)));
typedef float f32x4 __attribute__((ext_vector_type(4)));
typedef float f32x2 __attribute__((ext_vector_type(2)));

__device__ __forceinline__ float bf2f(ushort_t u){ return __uint_as_float(((unsigned)u)<<16); }
__device__ __forceinline__ ushort_t f2bf(float f){
  unsigned x = __float_as_uint(f);
  unsigned r = (x + 0x7fffu + ((x>>16)&1u)) >> 16;
  return (ushort_t)r;
}

// ---------------------------------------------------------------------------
// K1: init. blocks [0,8): wlr+bsum ; [8,72): Wf ; [72,..): zero counts.
// Wf[(((gat*4+kk)*8+f)*64+lane)*8+i] = lam[gat/2]*W[gat][kk*32+(lane>>4)*8+i][f*16+(lane&15)]
// ---------------------------------------------------------------------------
__global__ __launch_bounds__(256) void init_kernel(const float* __restrict__ W,
    const float* __restrict__ al, const float* __restrict__ ar,
    const float* __restrict__ bias, const float* __restrict__ lam,
    float* __restrict__ wl, float* __restrict__ wr, float* __restrict__ bsum,
    ushort_t* __restrict__ Wf, int* __restrict__ counts, int n) {
  int b = blockIdx.x;
  if (b < 8) {
    int i = b, j = threadIdx.x;
    if (j < 128) {
      const float* Wi  = W + ((size_t)i*128 + j)*128;
      const float* ali = al + i*128;
      const float* ari = ar + i*128;
      float sl = 0.f, sr = 0.f;
      for (int k = 0; k < 128; ++k) { float w = Wi[k]; sl += w*ali[k]; sr += w*ari[k]; }
      wl[i*128+j] = sl; wr[i*128+j] = sr;
      if (i == 0) {
        float bb = 0.f;
        for (int t = 0; t < 8; ++t) bb += lam[t>>1]*bias[t*128+j];
        bsum[j] = bb;
      }
    }
  } else if (b < 72) {
    int tid = (b-8)*256 + threadIdx.x;      // 16384 threads
    int gat  = tid >> 11;
    int kk   = (tid >> 9) & 3;
    int f    = (tid >> 6) & 7;
    int lane = tid & 63;
    float c = lam[gat >> 1];
    int krow = kk*32 + (lane >> 4)*8;
    int col  = f*16 + (lane & 15);
    ushort_t v[8];
#pragma unroll
    for (int i = 0; i < 8; ++i)
      v[i] = f2bf(c * W[((size_t)gat*128 + krow + i)*128 + col]);
    ushort_t* o = Wf + (size_t)tid*8;
#pragma unroll
    for (int i = 0; i < 8; ++i) o[i] = v[i];
  } else {
    int idx = ((b-72)*256 + threadIdx.x)*4;
    int total = 4*n;
    if (idx + 4 <= total) {
      int4 z = {0,0,0,0};
      *(int4*)(counts + idx) = z;
    } else {
      for (int q = idx; q < total; ++q) counts[q] = 0;
    }
  }
}

// ---------------------------------------------------------------------------
// K2: prep (blocks [0,npb)) + hist (blocks [npb, npb+8*G)).
// prep: att[n][16] ([0..7]=el,[8..15]=er) + fb[n][256] (fs row, fd row) bf16.
// hist: XCD-partitioned counting, int4 edge reads.
// ---------------------------------------------------------------------------
__global__ __launch_bounds__(256) void prep_hist_kernel(const float* __restrict__ fs,
    const float* __restrict__ fd, const float* __restrict__ wl, const float* __restrict__ wr,
    float* __restrict__ att, ushort_t* __restrict__ fb,
    const int* __restrict__ ia_s, const int* __restrict__ ia_d,
    const int* __restrict__ ie_s, const int* __restrict__ ie_d,
    int* __restrict__ counts, int n, int e, int n8, int npb, int G) {
  int b = blockIdx.x;
  if (b < npb) {
    int wid  = (b*256 + threadIdx.x) >> 6;
    int lane = threadIdx.x & 63;
    if (wid >= n) return;
    float2 s = *(const float2*)(fs + (size_t)wid*128 + lane*2);
    float2 d = *(const float2*)(fd + (size_t)wid*128 + lane*2);
    ushort2 us; us.x = f2bf(s.x); us.y = f2bf(s.y);
    ushort2 ud; ud.x = f2bf(d.x); ud.y = f2bf(d.y);
    *(ushort2*)(fb + (size_t)wid*256 + lane*2) = us;
    *(ushort2*)(fb + (size_t)wid*256 + 128 + lane*2) = ud;
#pragma unroll
    for (int i = 0; i < 8; ++i) {
      float2 wlv = *(const float2*)(wl + i*128 + lane*2);
      float2 wrv = *(const float2*)(wr + i*128 + lane*2);
      bool use_s = (i==0)||(i==1)||(i==4)||(i==5);
      float xx = use_s ? s.x : d.x;
      float xy = use_s ? s.y : d.y;
      float vl = xx*wlv.x + xy*wlv.y;
      float vr = d.x*wrv.x + d.y*wrv.y;
#pragma unroll
      for (int off = 32; off; off >>= 1) { vl += __shfl_xor(vl, off); vr += __shfl_xor(vr, off); }
      if (lane == 0) { att[(size_t)wid*16 + i] = vl; att[(size_t)wid*16 + 8 + i] = vr; }
    }
  } else {
    int bid = b - npb;
    int x = bid & 7;
    int lo = x*n8, hi = lo + n8; if (hi > n) hi = n;
    int tid = (bid >> 3)*256 + threadIdx.x;
    int nthr = G << 8;
#pragma unroll
    for (int g = 0; g < 4; ++g) {
      const int* dp = (g==0) ? ia_d : (g==1) ? ie_d : (g==2) ? ia_s : ie_s;
      int bo = g*n;
      for (int i = tid*4; i < e; i += nthr*4) {
        if (i + 4 <= e) {
          int4 d4 = *(const int4*)(dp + i);
          if (d4.x >= lo && d4.x < hi) atomicAdd(&counts[bo + d4.x], 1);
          if (d4.y >= lo && d4.y < hi) atomicAdd(&counts[bo + d4.y], 1);
          if (d4.z >= lo && d4.z < hi) atomicAdd(&counts[bo + d4.z], 1);
          if (d4.w >= lo && d4.w < hi) atomicAdd(&counts[bo + d4.w], 1);
        } else {
          for (int q = i; q < e; ++q) {
            int dv = dp[q];
            if (dv >= lo && dv < hi) atomicAdd(&counts[bo + dv], 1);
          }
        }
      }
    }
  }
}

// ---------------------------------------------------------------------------
// K3: per-1024-chunk local exclusive scan; bsums[chunk] = chunk total.
// ---------------------------------------------------------------------------
__global__ __launch_bounds__(256) void scan_local_kernel(const int* __restrict__ counts,
    int* __restrict__ rowptr, int* __restrict__ bsums, int total) {
  __shared__ int sh[256];
  int base = blockIdx.x*1024;
  int tid = threadIdx.x;
  int v[4]; int s = 0;
#pragma unroll
  for (int q = 0; q < 4; ++q) { int idx = base + tid*4 + q; int x = (idx < total) ? counts[idx] : 0; v[q] = x; s += x; }
  sh[tid] = s; __syncthreads();
  for (int off = 1; off < 256; off <<= 1) {
    int t2 = (tid >= off) ? sh[tid-off] : 0;
    __syncthreads();
    sh[tid] += t2;
    __syncthreads();
  }
  if (tid == 255) bsums[blockIdx.x] = sh[255];
  int run = sh[tid] - s;
#pragma unroll
  for (int q = 0; q < 4; ++q) { int idx = base + tid*4 + q; if (idx < total) rowptr[idx] = run; run += v[q]; }
}

// ---------------------------------------------------------------------------
// K4: finish scan. Every block redundantly scans bsums (nb<=1024) in LDS,
// then fixes up its 512 rowptr entries AND writes cursor (replaces memcpy).
// ---------------------------------------------------------------------------
__global__ __launch_bounds__(512) void scan_finish_kernel(int* __restrict__ rowptr,
    int* __restrict__ cursor, const int* __restrict__ bsums, int total, int nb, int grand) {
  __shared__ int sb[1024];
  __shared__ int ps[512];
  int tid = threadIdx.x;
  int v0 = (2*tid   < nb) ? bsums[2*tid]   : 0;
  int v1 = (2*tid+1 < nb) ? bsums[2*tid+1] : 0;
  int s = v0 + v1;
  ps[tid] = s; __syncthreads();
  for (int off = 1; off < 512; off <<= 1) {
    int t2 = (tid >= off) ? ps[tid-off] : 0;
    __syncthreads();
    ps[tid] += t2;
    __syncthreads();
  }
  int excl = ps[tid] - s;
  sb[2*tid] = excl; sb[2*tid+1] = excl + v0;
  __syncthreads();
  int idx = blockIdx.x*512 + tid;
  if (idx < total) {
    int v = rowptr[idx] + sb[idx >> 10];
    rowptr[idx] = v;
    cursor[idx] = v;
  }
  if (idx == total) rowptr[total] = grand;
}

// ---------------------------------------------------------------------------
// K5: fill. cursor preloaded with rowptr. XCD-partitioned, int4 edge reads.
// ---------------------------------------------------------------------------
__global__ __launch_bounds__(256) void fill_kernel(const int* __restrict__ ia_s,
    const int* __restrict__ ia_d, const int* __restrict__ ie_s, const int* __restrict__ ie_d,
    int* __restrict__ cursor, int* __restrict__ col, int n, int e, int n8, int G) {
  int bid = blockIdx.x;
  int x = bid & 7;
  int lo = x*n8, hi = lo + n8; if (hi > n) hi = n;
  int tid = (bid >> 3)*256 + threadIdx.x;
  int nthr = G << 8;
#pragma unroll
  for (int g = 0; g < 4; ++g) {
    const int* dp = (g==0) ? ia_d : (g==1) ? ie_d : (g==2) ? ia_s : ie_s;
    const int* sp = (g==0) ? ia_s : (g==1) ? ie_s : (g==2) ? ia_d : ie_d;
    int bo = g*n;
    for (int i = tid*4; i < e; i += nthr*4) {
      if (i + 4 <= e) {
        int4 d4 = *(const int4*)(dp + i);
        bool m0 = d4.x >= lo && d4.x < hi;
        bool m1 = d4.y >= lo && d4.y < hi;
        bool m2 = d4.z >= lo && d4.z < hi;
        bool m3 = d4.w >= lo && d4.w < hi;
        if (m0 | m1 | m2 | m3) {
          int4 s4 = *(const int4*)(sp + i);
          if (m0) { int pos = atomicAdd(&cursor[bo + d4.x], 1); col[pos] = s4.x; }
          if (m1) { int pos = atomicAdd(&cursor[bo + d4.y], 1); col[pos] = s4.y; }
          if (m2) { int pos = atomicAdd(&cursor[bo + d4.z], 1); col[pos] = s4.z; }
          if (m3) { int pos = atomicAdd(&cursor[bo + d4.w], 1); col[pos] = s4.w; }
        }
      } else {
        for (int q = i; q < e; ++q) {
          int dv = dp[q];
          if (dv >= lo && dv < hi) {
            int pos = atomicAdd(&cursor[bo + dv], 1);
            col[pos] = sp[q];
          }
        }
      }
    }
  }
}

// ---------------------------------------------------------------------------
// K6: fused aggregation + MFMA GEMM + epilogue. Block = 16 dsts, 8 waves.
// Agg: wave w -> graph g=w>>1, dst-subset w&1 (8 dsts); lanes split 32|32
//   into 2 edge slots; within a slot, lane covers 8 features (u32x4 load),
//   l<16 -> fs/pa(gatA), l>=16 -> fd/pb(gatB). f32x2 packed accumulate
//   (v_pk_fma_f32). 2-stage pipelined edge loop. Merge halves via shfl(32).
// MFMA: wave w owns col-frag f=w, K=1024 over XOR-swizzled LDS A-tile.
// Epilogue: out = C + rc*fd(bf16 from fb) + bsum, written once.
// ---------------------------------------------------------------------------
__global__ __launch_bounds__(512) void fused_kernel(const ushort_t* __restrict__ fb,
    const float* __restrict__ att, const int* __restrict__ rowptr,
    const int* __restrict__ col, const ushort_t* __restrict__ Wf,
    const float* __restrict__ lam, const float* __restrict__ bsum,
    float* __restrict__ out, int n) {
  __shared__ ushort_t As[16*1024];
  int t = threadIdx.x, w = t >> 6, lane = t & 63;
  int base = blockIdx.x*16;
  int g = w >> 1;
  int gatA = (g < 2) ? g : g + 2;
  int half = lane >> 5;
  int l    = lane & 31;
  int typ  = (l >> 4) & 1;
  int gat  = gatA + 2*typ;

  for (int i = 0; i < 8; ++i) {
    int di = (w & 1)*8 + i;
    int d = base + di; if (d >= n) d = n - 1;
    int row = rowptr[(size_t)g*n + d], end = rowptr[(size_t)g*n + d + 1];
    float er_ = att[(size_t)d*16 + 8 + gat];
    f32x2 acc0 = {0.f,0.f}, acc1 = {0.f,0.f}, acc2 = {0.f,0.f}, acc3 = {0.f,0.f};
    float den = 0.f;
    int e2 = row + half;
    int sC = 0; float elC = 0.f; u32x4 uC = {0,0,0,0};
    if (e2 < end) {
      sC  = col[e2];
      elC = att[(size_t)sC*16 + gat];
      uC  = *reinterpret_cast<const u32x4*>(fb + (size_t)sC*256 + l*8);
    }
    while (e2 < end) {
      int eN = e2 + 2;
      int sN = sC; float elN = elC; u32x4 uN = uC;
      if (eN < end) {
        sN  = col[eN];
        elN = att[(size_t)sN*16 + gat];
        uN  = *reinterpret_cast<const u32x4*>(fb + (size_t)sN*256 + l*8);
      }
      float ev = elC + er_;
      ev = (ev > 0.f) ? ev : 0.2f*ev;
      float p = __expf(ev);
      den += p;
      f32x2 pv = {p, p};
      f32x2 x0, x1, x2, x3;
      x0[0] = __uint_as_float(uC[0] << 16); x0[1] = __uint_as_float(uC[0] & 0xffff0000u);
      x1[0] = __uint_as_float(uC[1] << 16); x1[1] = __uint_as_float(uC[1] & 0xffff0000u);
      x2[0] = __uint_as_float(uC[2] << 16); x2[1] = __uint_as_float(uC[2] & 0xffff0000u);
      x3[0] = __uint_as_float(uC[3] << 16); x3[1] = __uint_as_float(uC[3] & 0xffff0000u);
      acc0 += pv*x0; acc1 += pv*x1; acc2 += pv*x2; acc3 += pv*x3;
      e2 = eN; sC = sN; elC = elN; uC = uN;
    }
    den += __shfl_xor(den, 32);
    acc0[0] += __shfl_xor(acc0[0], 32); acc0[1] += __shfl_xor(acc0[1], 32);
    acc1[0] += __shfl_xor(acc1[0], 32); acc1[1] += __shfl_xor(acc1[1], 32);
    acc2[0] += __shfl_xor(acc2[0], 32); acc2[1] += __shfl_xor(acc2[1], 32);
    acc3[0] += __shfl_xor(acc3[0], 32); acc3[1] += __shfl_xor(acc3[1], 32);
    if (half == 0) {
      float r = 1.f/fmaxf(den, 1e-9f);
      u16x8 o;
      o[0]=f2bf(acc0[0]*r); o[1]=f2bf(acc0[1]*r); o[2]=f2bf(acc1[0]*r); o[3]=f2bf(acc1[1]*r);
      o[4]=f2bf(acc2[0]*r); o[5]=f2bf(acc2[1]*r); o[6]=f2bf(acc3[0]*r); o[7]=f2bf(acc3[1]*r);
      int k = g*256 + l*8;
      int idx = di*1024 + (k ^ ((di & 7) << 3));
      *reinterpret_cast<u16x8*>(As + idx) = o;
    }
  }
  __syncthreads();

  int lr = lane & 15, lg = lane >> 4;
  f32x4 c0 = {0.f,0.f,0.f,0.f};
#pragma unroll
  for (int ks = 0; ks < 32; ++ks) {
    int kc = ks*32 + lg*8;
    int idx = lr*1024 + (kc ^ ((lr & 7) << 3));
    bf16x8 a = *reinterpret_cast<const bf16x8*>(As + idx);
    int wp = ks >> 3, sub = ks & 7;
    int gg = ((sub >= 4) ? 2 : 0) + ((wp < 2) ? wp : wp + 2);
    int kk = sub & 3;
    const ushort_t* bp = Wf + (((size_t)(gg*4 + kk)*8 + w)*64 + lane)*8;
    bf16x8 b0 = *reinterpret_cast<const bf16x8*>(bp);
    c0 = __builtin_amdgcn_mfma_f32_16x16x32_bf16(a, b0, c0, 0, 0, 0);
  }
  float rc = 2.f*(lam[0] + lam[1] + lam[2] + lam[3]);
  int gc = w*16 + lr;
#pragma unroll
  for (int r2 = 0; r2 < 4; ++r2) {
    int gr = base + lg*4 + r2;
    if (gr < n) {
      size_t o = (size_t)gr*128 + gc;
      float fdv = bf2f(fb[(size_t)gr*256 + 128 + gc]);
      out[o] = c0[r2] + rc*fdv + bsum[gc];
    }
  }
}

// ---------------------------------------------------------------------------
extern "C" void kernel_launch(void* const* d_in, const int* in_sizes, int n_in,
                              void* d_out, int out_size, void* d_ws, size_t ws_size,
                              hipStream_t stream) {
  const float* fs  = (const float*)d_in[0];
  const float* fd  = (const float*)d_in[1];
  const int* ia_s  = (const int*)d_in[2];
  const int* ia_d  = (const int*)d_in[3];
  const int* ie_s  = (const int*)d_in[4];
  const int* ie_d  = (const int*)d_in[5];
  const float* W   = (const float*)d_in[6];
  const float* al  = (const float*)d_in[7];
  const float* ar  = (const float*)d_in[8];
  const float* bias= (const float*)d_in[9];
  const float* lam = (const float*)d_in[10];
  int n = in_sizes[0] / 128;
  int e = in_sizes[2];
  float* out = (float*)d_out;

  char* ws = (char*)d_ws;
  size_t off = 0;
  auto alloc = [&](size_t bytes) -> char* { char* p = ws + off; off += (bytes + 255) & ~(size_t)255; return p; };
  float* wl      = (float*)alloc((size_t)8*128*4);
  float* wr      = (float*)alloc((size_t)8*128*4);
  float* bsum    = (float*)alloc(128*4);
  float* att     = (float*)alloc((size_t)n*16*4);
  int*   counts  = (int*)alloc((size_t)4*n*4);          // reused as cursor
  int*   rowptr  = (int*)alloc(((size_t)4*n + 1)*4);
  int*   bsums   = (int*)alloc(4096);
  int*   colv    = (int*)alloc((size_t)4*e*4);
  ushort_t* Wf   = (ushort_t*)alloc((size_t)8*128*128*2);
  ushort_t* fb   = (ushort_t*)alloc((size_t)n*256*2);
  (void)ws_size; (void)n_in; (void)out_size;

  int n8 = (n + 7)/8;
  int total = 4*n;
  int nb = (total + 1023)/1024;                 // scan chunks (<=1024 supported)
  int nZ = (total + 1023)/1024;                 // zero-blocks (1024 ints each)
  int npb = (n + 3)/4;                          // prep blocks
  int G = 160;                                  // edge-scan groups per partition

  hipLaunchKernelGGL(init_kernel, dim3(72 + nZ), dim3(256), 0, stream,
                     W, al, ar, bias, lam, wl, wr, bsum, Wf, counts, n);
  hipLaunchKernelGGL(prep_hist_kernel, dim3(npb + 8*G), dim3(256), 0, stream,
                     fs, fd, wl, wr, att, fb, ia_s, ia_d, ie_s, ie_d,
                     counts, n, e, n8, npb, G);
  hipLaunchKernelGGL(scan_local_kernel, dim3(nb), dim3(256), 0, stream,
                     counts, rowptr, bsums, total);
  hipLaunchKernelGGL(scan_finish_kernel, dim3((total + 512)/512), dim3(512), 0, stream,
                     rowptr, counts, bsums, total, nb, 4*e);
  hipLaunchKernelGGL(fill_kernel, dim3(8*G), dim3(256), 0, stream,
                     ia_s, ia_d, ie_s, ie_d, counts, colv, n, e, n8, G);
  hipLaunchKernelGGL(fused_kernel, dim3((n+15)/16), dim3(512), 0, stream,
                     fb, att, rowptr, colv, Wf, lam, bsum, out, n);
}

// Round 7
// 706.081 us; speedup vs baseline: 2.2456x; 1.0060x over previous
//
#include <hip/hip_runtime.h>
#include <hip/hip_bf16.h>

typedef unsigned short ushort_t;
typedef __bf16 bf16x8 __attribute__((ext_vector_type(8)));
typedef ushort_t u16x8 __attribute__((ext_vector_type(8)));
typedef unsigned int u32x4 __attribute__((ext_vector_type(4)));
typedef float f32x4 __attribute__((ext_vector_type(4)));
typedef float f32x2 __attribute__((ext_vector_type(2)));

__device__ __forceinline__ float bf2f(ushort_t u){ return __uint_as_float(((unsigned)u)<<16); }
__device__ __forceinline__ ushort_t f2bf(float f){
  unsigned x = __float_as_uint(f);
  unsigned r = (x + 0x7fffu + ((x>>16)&1u)) >> 16;
  return (ushort_t)r;
}

// ---------------------------------------------------------------------------
// K1: init. blocks [0,8): wlr+bsum ; [8,72): Wf ; [72,..): zero counts.
// Wf[(((gat*4+kk)*8+f)*64+lane)*8+i] = lam[gat/2]*W[gat][kk*32+(lane>>4)*8+i][f*16+(lane&15)]
// ---------------------------------------------------------------------------
__global__ __launch_bounds__(256) void init_kernel(const float* __restrict__ W,
    const float* __restrict__ al, const float* __restrict__ ar,
    const float* __restrict__ bias, const float* __restrict__ lam,
    float* __restrict__ wl, float* __restrict__ wr, float* __restrict__ bsum,
    ushort_t* __restrict__ Wf, int* __restrict__ counts, int n) {
  int b = blockIdx.x;
  if (b < 8) {
    int i = b, j = threadIdx.x;
    if (j < 128) {
      const float* Wi  = W + ((size_t)i*128 + j)*128;
      const float* ali = al + i*128;
      const float* ari = ar + i*128;
      float sl = 0.f, sr = 0.f;
      for (int k = 0; k < 128; ++k) { float w = Wi[k]; sl += w*ali[k]; sr += w*ari[k]; }
      wl[i*128+j] = sl; wr[i*128+j] = sr;
      if (i == 0) {
        float bb = 0.f;
        for (int t = 0; t < 8; ++t) bb += lam[t>>1]*bias[t*128+j];
        bsum[j] = bb;
      }
    }
  } else if (b < 72) {
    int tid = (b-8)*256 + threadIdx.x;      // 16384 threads
    int gat  = tid >> 11;
    int kk   = (tid >> 9) & 3;
    int f    = (tid >> 6) & 7;
    int lane = tid & 63;
    float c = lam[gat >> 1];
    int krow = kk*32 + (lane >> 4)*8;
    int col  = f*16 + (lane & 15);
    ushort_t v[8];
#pragma unroll
    for (int i = 0; i < 8; ++i)
      v[i] = f2bf(c * W[((size_t)gat*128 + krow + i)*128 + col]);
    ushort_t* o = Wf + (size_t)tid*8;
#pragma unroll
    for (int i = 0; i < 8; ++i) o[i] = v[i];
  } else {
    int idx = ((b-72)*256 + threadIdx.x)*4;
    int total = 4*n;
    if (idx + 4 <= total) {
      int4 z = {0,0,0,0};
      *(int4*)(counts + idx) = z;
    } else {
      for (int q = idx; q < total; ++q) counts[q] = 0;
    }
  }
}

// ---------------------------------------------------------------------------
// K2: prep (blocks [0,npb)) + hist (blocks [npb, npb+8*G)).
// prep: att[n][16] ([0..7]=el,[8..15]=er) + fb[n][256] (fs row, fd row) bf16.
// hist: XCD-partitioned counting, int4 edge reads.
// ---------------------------------------------------------------------------
__global__ __launch_bounds__(256) void prep_hist_kernel(const float* __restrict__ fs,
    const float* __restrict__ fd, const float* __restrict__ wl, const float* __restrict__ wr,
    float* __restrict__ att, ushort_t* __restrict__ fb,
    const int* __restrict__ ia_s, const int* __restrict__ ia_d,
    const int* __restrict__ ie_s, const int* __restrict__ ie_d,
    int* __restrict__ counts, int n, int e, int n8, int npb, int G) {
  int b = blockIdx.x;
  if (b < npb) {
    int wid  = (b*256 + threadIdx.x) >> 6;
    int lane = threadIdx.x & 63;
    if (wid >= n) return;
    float2 s = *(const float2*)(fs + (size_t)wid*128 + lane*2);
    float2 d = *(const float2*)(fd + (size_t)wid*128 + lane*2);
    ushort2 us; us.x = f2bf(s.x); us.y = f2bf(s.y);
    ushort2 ud; ud.x = f2bf(d.x); ud.y = f2bf(d.y);
    *(ushort2*)(fb + (size_t)wid*256 + lane*2) = us;
    *(ushort2*)(fb + (size_t)wid*256 + 128 + lane*2) = ud;
#pragma unroll
    for (int i = 0; i < 8; ++i) {
      float2 wlv = *(const float2*)(wl + i*128 + lane*2);
      float2 wrv = *(const float2*)(wr + i*128 + lane*2);
      bool use_s = (i==0)||(i==1)||(i==4)||(i==5);
      float xx = use_s ? s.x : d.x;
      float xy = use_s ? s.y : d.y;
      float vl = xx*wlv.x + xy*wlv.y;
      float vr = d.x*wrv.x + d.y*wrv.y;
#pragma unroll
      for (int off = 32; off; off >>= 1) { vl += __shfl_xor(vl, off); vr += __shfl_xor(vr, off); }
      if (lane == 0) { att[(size_t)wid*16 + i] = vl; att[(size_t)wid*16 + 8 + i] = vr; }
    }
  } else {
    int bid = b - npb;
    int x = bid & 7;
    int lo = x*n8, hi = lo + n8; if (hi > n) hi = n;
    int tid = (bid >> 3)*256 + threadIdx.x;
    int nthr = G << 8;
#pragma unroll
    for (int g = 0; g < 4; ++g) {
      const int* dp = (g==0) ? ia_d : (g==1) ? ie_d : (g==2) ? ia_s : ie_s;
      int bo = g*n;
      for (int i = tid*4; i < e; i += nthr*4) {
        if (i + 4 <= e) {
          int4 d4 = *(const int4*)(dp + i);
          if (d4.x >= lo && d4.x < hi) atomicAdd(&counts[bo + d4.x], 1);
          if (d4.y >= lo && d4.y < hi) atomicAdd(&counts[bo + d4.y], 1);
          if (d4.z >= lo && d4.z < hi) atomicAdd(&counts[bo + d4.z], 1);
          if (d4.w >= lo && d4.w < hi) atomicAdd(&counts[bo + d4.w], 1);
        } else {
          for (int q = i; q < e; ++q) {
            int dv = dp[q];
            if (dv >= lo && dv < hi) atomicAdd(&counts[bo + dv], 1);
          }
        }
      }
    }
  }
}

// ---------------------------------------------------------------------------
// K3: per-1024-chunk local exclusive scan; bsums[chunk] = chunk total.
// ---------------------------------------------------------------------------
__global__ __launch_bounds__(256) void scan_local_kernel(const int* __restrict__ counts,
    int* __restrict__ rowptr, int* __restrict__ bsums, int total) {
  __shared__ int sh[256];
  int base = blockIdx.x*1024;
  int tid = threadIdx.x;
  int v[4]; int s = 0;
#pragma unroll
  for (int q = 0; q < 4; ++q) { int idx = base + tid*4 + q; int x = (idx < total) ? counts[idx] : 0; v[q] = x; s += x; }
  sh[tid] = s; __syncthreads();
  for (int off = 1; off < 256; off <<= 1) {
    int t2 = (tid >= off) ? sh[tid-off] : 0;
    __syncthreads();
    sh[tid] += t2;
    __syncthreads();
  }
  if (tid == 255) bsums[blockIdx.x] = sh[255];
  int run = sh[tid] - s;
#pragma unroll
  for (int q = 0; q < 4; ++q) { int idx = base + tid*4 + q; if (idx < total) rowptr[idx] = run; run += v[q]; }
}

// ---------------------------------------------------------------------------
// K4: finish scan. Every block redundantly scans bsums (nb<=1024) in LDS,
// then fixes up its 512 rowptr entries AND writes cursor.
// ---------------------------------------------------------------------------
__global__ __launch_bounds__(512) void scan_finish_kernel(int* __restrict__ rowptr,
    int* __restrict__ cursor, const int* __restrict__ bsums, int total, int nb, int grand) {
  __shared__ int sb[1024];
  __shared__ int ps[512];
  int tid = threadIdx.x;
  int v0 = (2*tid   < nb) ? bsums[2*tid]   : 0;
  int v1 = (2*tid+1 < nb) ? bsums[2*tid+1] : 0;
  int s = v0 + v1;
  ps[tid] = s; __syncthreads();
  for (int off = 1; off < 512; off <<= 1) {
    int t2 = (tid >= off) ? ps[tid-off] : 0;
    __syncthreads();
    ps[tid] += t2;
    __syncthreads();
  }
  int excl = ps[tid] - s;
  sb[2*tid] = excl; sb[2*tid+1] = excl + v0;
  __syncthreads();
  int idx = blockIdx.x*512 + tid;
  if (idx < total) {
    int v = rowptr[idx] + sb[idx >> 10];
    rowptr[idx] = v;
    cursor[idx] = v;
  }
  if (idx == total) rowptr[total] = grand;
}

// ---------------------------------------------------------------------------
// K5: fill + attention-weight precompute. cursor preloaded with rowptr.
// XCD-partitioned, int4 edge reads. Per in-range edge: gather att[s] line
// (scattered) + att[d] er values (partition-local, L2-hot), compute
// leakyrelu+exp for both gats, pack epk[pos] = {s, bf16(pa)|bf16(pb)<<16}.
// ---------------------------------------------------------------------------
__global__ __launch_bounds__(256) void fill_kernel(const int* __restrict__ ia_s,
    const int* __restrict__ ia_d, const int* __restrict__ ie_s, const int* __restrict__ ie_d,
    const float* __restrict__ att, int* __restrict__ cursor, int2* __restrict__ epk,
    int n, int e, int n8, int G) {
  int bid = blockIdx.x;
  int x = bid & 7;
  int lo = x*n8, hi = lo + n8; if (hi > n) hi = n;
  int tid = (bid >> 3)*256 + threadIdx.x;
  int nthr = G << 8;
#pragma unroll
  for (int g = 0; g < 4; ++g) {
    const int* dp = (g==0) ? ia_d : (g==1) ? ie_d : (g==2) ? ia_s : ie_s;
    const int* sp = (g==0) ? ia_s : (g==1) ? ie_s : (g==2) ? ia_d : ie_d;
    int gatA = (g < 2) ? g : g + 2;
    int gatB = gatA + 2;
    int bo = g*n;
    for (int i = tid*4; i < e; i += nthr*4) {
      int lim = (i + 4 <= e) ? 4 : (e - i);
      if (lim == 4) {
        int4 d4 = *(const int4*)(dp + i);
        bool m0 = d4.x >= lo && d4.x < hi;
        bool m1 = d4.y >= lo && d4.y < hi;
        bool m2 = d4.z >= lo && d4.z < hi;
        bool m3 = d4.w >= lo && d4.w < hi;
        if (m0 | m1 | m2 | m3) {
          int4 s4 = *(const int4*)(sp + i);
          int dv[4] = {d4.x, d4.y, d4.z, d4.w};
          int sv[4] = {s4.x, s4.y, s4.z, s4.w};
          bool mv[4] = {m0, m1, m2, m3};
#pragma unroll
          for (int q = 0; q < 4; ++q) {
            if (mv[q]) {
              int dd = dv[q], ss = sv[q];
              float ea = att[(size_t)ss*16 + gatA] + att[(size_t)dd*16 + 8 + gatA];
              float eb = att[(size_t)ss*16 + gatB] + att[(size_t)dd*16 + 8 + gatB];
              ea = (ea > 0.f) ? ea : 0.2f*ea;
              eb = (eb > 0.f) ? eb : 0.2f*eb;
              unsigned p2 = (unsigned)f2bf(__expf(ea)) | ((unsigned)f2bf(__expf(eb)) << 16);
              int pos = atomicAdd(&cursor[bo + dd], 1);
              epk[pos] = make_int2(ss, (int)p2);
            }
          }
        }
      } else {
        for (int q = i; q < e; ++q) {
          int dd = dp[q];
          if (dd >= lo && dd < hi) {
            int ss = sp[q];
            float ea = att[(size_t)ss*16 + gatA] + att[(size_t)dd*16 + 8 + gatA];
            float eb = att[(size_t)ss*16 + gatB] + att[(size_t)dd*16 + 8 + gatB];
            ea = (ea > 0.f) ? ea : 0.2f*ea;
            eb = (eb > 0.f) ? eb : 0.2f*eb;
            unsigned p2 = (unsigned)f2bf(__expf(ea)) | ((unsigned)f2bf(__expf(eb)) << 16);
            int pos = atomicAdd(&cursor[bo + dd], 1);
            epk[pos] = make_int2(ss, (int)p2);
          }
        }
      }
    }
  }
}

// ---------------------------------------------------------------------------
// K6: fused aggregation + MFMA GEMM + epilogue. Block = 16 dsts, 8 waves.
// Agg: wave w -> graph g=w>>1, dst-subset w&1 (8 dsts); lanes split 32|32
//   into 2 edge slots; within a slot, lane covers 8 features (u32x4 load),
//   l<16 -> fs/pa(gatA), l>=16 -> fd/pb(gatB). Inner loop: one 8B epk read
//   (s + packed bf16 weights, precomputed in fill) -> fb row gather -> pk_fma.
//   No att gather, no exp in the hot loop. 2-stage pipelined.
// MFMA: wave w owns col-frag f=w, K=1024 over XOR-swizzled LDS A-tile.
// Epilogue: out = C + rc*fd(bf16 from fb) + bsum, written once.
// ---------------------------------------------------------------------------
__global__ __launch_bounds__(512) void fused_kernel(const ushort_t* __restrict__ fb,
    const int* __restrict__ rowptr, const int2* __restrict__ epk,
    const ushort_t* __restrict__ Wf, const float* __restrict__ lam,
    const float* __restrict__ bsum, float* __restrict__ out, int n) {
  __shared__ ushort_t As[16*1024];
  int t = threadIdx.x, w = t >> 6, lane = t & 63;
  int base = blockIdx.x*16;
  int g = w >> 1;
  int half = lane >> 5;
  int l    = lane & 31;
  int typ  = (l >> 4) & 1;

  for (int i = 0; i < 8; ++i) {
    int di = (w & 1)*8 + i;
    int d = base + di; if (d >= n) d = n - 1;
    int row = rowptr[(size_t)g*n + d], end = rowptr[(size_t)g*n + d + 1];
    f32x2 acc0 = {0.f,0.f}, acc1 = {0.f,0.f}, acc2 = {0.f,0.f}, acc3 = {0.f,0.f};
    float den = 0.f;
    int e2 = row + half;
    int2 eC = {0, 0}; u32x4 uC = {0,0,0,0};
    if (e2 < end) {
      eC = epk[e2];
      uC = *reinterpret_cast<const u32x4*>(fb + (size_t)eC.x*256 + l*8);
    }
    while (e2 < end) {
      int eN = e2 + 2;
      int2 eT = eC; u32x4 uN = uC;
      if (eN < end) {
        eT = epk[eN];
        uN = *reinterpret_cast<const u32x4*>(fb + (size_t)eT.x*256 + l*8);
      }
      unsigned p2 = (unsigned)eC.y;
      float p = typ ? __uint_as_float(p2 & 0xffff0000u)
                    : __uint_as_float(p2 << 16);
      den += p;
      f32x2 pv = {p, p};
      f32x2 x0, x1, x2, x3;
      x0[0] = __uint_as_float(uC[0] << 16); x0[1] = __uint_as_float(uC[0] & 0xffff0000u);
      x1[0] = __uint_as_float(uC[1] << 16); x1[1] = __uint_as_float(uC[1] & 0xffff0000u);
      x2[0] = __uint_as_float(uC[2] << 16); x2[1] = __uint_as_float(uC[2] & 0xffff0000u);
      x3[0] = __uint_as_float(uC[3] << 16); x3[1] = __uint_as_float(uC[3] & 0xffff0000u);
      acc0 += pv*x0; acc1 += pv*x1; acc2 += pv*x2; acc3 += pv*x3;
      e2 = eN; eC = eT; uC = uN;
    }
    den += __shfl_xor(den, 32);
    acc0[0] += __shfl_xor(acc0[0], 32); acc0[1] += __shfl_xor(acc0[1], 32);
    acc1[0] += __shfl_xor(acc1[0], 32); acc1[1] += __shfl_xor(acc1[1], 32);
    acc2[0] += __shfl_xor(acc2[0], 32); acc2[1] += __shfl_xor(acc2[1], 32);
    acc3[0] += __shfl_xor(acc3[0], 32); acc3[1] += __shfl_xor(acc3[1], 32);
    if (half == 0) {
      float r = 1.f/fmaxf(den, 1e-9f);
      u16x8 o;
      o[0]=f2bf(acc0[0]*r); o[1]=f2bf(acc0[1]*r); o[2]=f2bf(acc1[0]*r); o[3]=f2bf(acc1[1]*r);
      o[4]=f2bf(acc2[0]*r); o[5]=f2bf(acc2[1]*r); o[6]=f2bf(acc3[0]*r); o[7]=f2bf(acc3[1]*r);
      int k = g*256 + l*8;
      int idx = di*1024 + (k ^ ((di & 7) << 3));
      *reinterpret_cast<u16x8*>(As + idx) = o;
    }
  }
  __syncthreads();

  int lr = lane & 15, lg = lane >> 4;
  f32x4 c0 = {0.f,0.f,0.f,0.f};
#pragma unroll
  for (int ks = 0; ks < 32; ++ks) {
    int kc = ks*32 + lg*8;
    int idx = lr*1024 + (kc ^ ((lr & 7) << 3));
    bf16x8 a = *reinterpret_cast<const bf16x8*>(As + idx);
    int wp = ks >> 3, sub = ks & 7;
    int gg = ((sub >= 4) ? 2 : 0) + ((wp < 2) ? wp : wp + 2);
    int kk = sub & 3;
    const ushort_t* bp = Wf + (((size_t)(gg*4 + kk)*8 + w)*64 + lane)*8;
    bf16x8 b0 = *reinterpret_cast<const bf16x8*>(bp);
    c0 = __builtin_amdgcn_mfma_f32_16x16x32_bf16(a, b0, c0, 0, 0, 0);
  }
  float rc = 2.f*(lam[0] + lam[1] + lam[2] + lam[3]);
  int gc = w*16 + lr;
#pragma unroll
  for (int r2 = 0; r2 < 4; ++r2) {
    int gr = base + lg*4 + r2;
    if (gr < n) {
      size_t o = (size_t)gr*128 + gc;
      float fdv = bf2f(fb[(size_t)gr*256 + 128 + gc]);
      out[o] = c0[r2] + rc*fdv + bsum[gc];
    }
  }
}

// ---------------------------------------------------------------------------
extern "C" void kernel_launch(void* const* d_in, const int* in_sizes, int n_in,
                              void* d_out, int out_size, void* d_ws, size_t ws_size,
                              hipStream_t stream) {
  const float* fs  = (const float*)d_in[0];
  const float* fd  = (const float*)d_in[1];
  const int* ia_s  = (const int*)d_in[2];
  const int* ia_d  = (const int*)d_in[3];
  const int* ie_s  = (const int*)d_in[4];
  const int* ie_d  = (const int*)d_in[5];
  const float* W   = (const float*)d_in[6];
  const float* al  = (const float*)d_in[7];
  const float* ar  = (const float*)d_in[8];
  const float* bias= (const float*)d_in[9];
  const float* lam = (const float*)d_in[10];
  int n = in_sizes[0] / 128;
  int e = in_sizes[2];
  float* out = (float*)d_out;

  char* ws = (char*)d_ws;
  size_t off = 0;
  auto alloc = [&](size_t bytes) -> char* { char* p = ws + off; off += (bytes + 255) & ~(size_t)255; return p; };
  float* wl      = (float*)alloc((size_t)8*128*4);
  float* wr      = (float*)alloc((size_t)8*128*4);
  float* bsum    = (float*)alloc(128*4);
  float* att     = (float*)alloc((size_t)n*16*4);
  int*   counts  = (int*)alloc((size_t)4*n*4);          // reused as cursor
  int*   rowptr  = (int*)alloc(((size_t)4*n + 1)*4);
  int*   bsums   = (int*)alloc(4096);
  int2*  epk     = (int2*)alloc((size_t)4*e*8);
  ushort_t* Wf   = (ushort_t*)alloc((size_t)8*128*128*2);
  ushort_t* fb   = (ushort_t*)alloc((size_t)n*256*2);
  (void)ws_size; (void)n_in; (void)out_size;

  int n8 = (n + 7)/8;
  int total = 4*n;
  int nb = (total + 1023)/1024;                 // scan chunks (<=1024 supported)
  int nZ = (total + 1023)/1024;                 // zero-blocks (1024 ints each)
  int npb = (n + 3)/4;                          // prep blocks
  int G = 160;                                  // edge-scan groups per partition

  hipLaunchKernelGGL(init_kernel, dim3(72 + nZ), dim3(256), 0, stream,
                     W, al, ar, bias, lam, wl, wr, bsum, Wf, counts, n);
  hipLaunchKernelGGL(prep_hist_kernel, dim3(npb + 8*G), dim3(256), 0, stream,
                     fs, fd, wl, wr, att, fb, ia_s, ia_d, ie_s, ie_d,
                     counts, n, e, n8, npb, G);
  hipLaunchKernelGGL(scan_local_kernel, dim3(nb), dim3(256), 0, stream,
                     counts, rowptr, bsums, total);
  hipLaunchKernelGGL(scan_finish_kernel, dim3((total + 512)/512), dim3(512), 0, stream,
                     rowptr, counts, bsums, total, nb, 4*e);
  hipLaunchKernelGGL(fill_kernel, dim3(8*G), dim3(256), 0, stream,
                     ia_s, ia_d, ie_s, ie_d, att, counts, epk, n, e, n8, G);
  hipLaunchKernelGGL(fused_kernel, dim3((n+15)/16), dim3(512), 0, stream,
                     fb, rowptr, epk, Wf, lam, bsum, out, n);
}

// Round 8
// 659.061 us; speedup vs baseline: 2.4058x; 1.0713x over previous
//
#include <hip/hip_runtime.h>
#include <hip/hip_bf16.h>

typedef unsigned short ushort_t;
typedef unsigned char uchar_t;
typedef __bf16 bf16x8 __attribute__((ext_vector_type(8)));
typedef ushort_t u16x8 __attribute__((ext_vector_type(8)));
typedef unsigned int u32x2 __attribute__((ext_vector_type(2)));
typedef float f32x4 __attribute__((ext_vector_type(4)));
typedef float f32x2 __attribute__((ext_vector_type(2)));

__device__ __forceinline__ float bf2f(ushort_t u){ return __uint_as_float(((unsigned)u)<<16); }
__device__ __forceinline__ ushort_t f2bf(float f){
  unsigned x = __float_as_uint(f);
  unsigned r = (x + 0x7fffu + ((x>>16)&1u)) >> 16;
  return (ushort_t)r;
}

// ---------------------------------------------------------------------------
// K1: init. blocks [0,8): wlr+bsum ; [8,72): Wf ; [72,..): zero counts.
// Wf[(((gat*4+kk)*8+f)*64+lane)*8+i] = lam[gat/2]*W[gat][kk*32+(lane>>4)*8+i][f*16+(lane&15)]
// ---------------------------------------------------------------------------
__global__ __launch_bounds__(256) void init_kernel(const float* __restrict__ W,
    const float* __restrict__ al, const float* __restrict__ ar,
    const float* __restrict__ bias, const float* __restrict__ lam,
    float* __restrict__ wl, float* __restrict__ wr, float* __restrict__ bsum,
    ushort_t* __restrict__ Wf, int* __restrict__ counts, int n) {
  int b = blockIdx.x;
  if (b < 8) {
    int i = b, j = threadIdx.x;
    if (j < 128) {
      const float* Wi  = W + ((size_t)i*128 + j)*128;
      const float* ali = al + i*128;
      const float* ari = ar + i*128;
      float sl = 0.f, sr = 0.f;
      for (int k = 0; k < 128; ++k) { float w = Wi[k]; sl += w*ali[k]; sr += w*ari[k]; }
      wl[i*128+j] = sl; wr[i*128+j] = sr;
      if (i == 0) {
        float bb = 0.f;
        for (int t = 0; t < 8; ++t) bb += lam[t>>1]*bias[t*128+j];
        bsum[j] = bb;
      }
    }
  } else if (b < 72) {
    int tid = (b-8)*256 + threadIdx.x;      // 16384 threads
    int gat  = tid >> 11;
    int kk   = (tid >> 9) & 3;
    int f    = (tid >> 6) & 7;
    int lane = tid & 63;
    float c = lam[gat >> 1];
    int krow = kk*32 + (lane >> 4)*8;
    int col  = f*16 + (lane & 15);
    ushort_t v[8];
#pragma unroll
    for (int i = 0; i < 8; ++i)
      v[i] = f2bf(c * W[((size_t)gat*128 + krow + i)*128 + col]);
    ushort_t* o = Wf + (size_t)tid*8;
#pragma unroll
    for (int i = 0; i < 8; ++i) o[i] = v[i];
  } else {
    int idx = ((b-72)*256 + threadIdx.x)*4;
    int total = 4*n;
    if (idx + 4 <= total) {
      int4 z = {0,0,0,0};
      *(int4*)(counts + idx) = z;
    } else {
      for (int q = idx; q < total; ++q) counts[q] = 0;
    }
  }
}

// ---------------------------------------------------------------------------
// K2: prep (blocks [0,npb)) + hist (blocks [npb, npb+8*G)).
// prep: per-graph packed attention tables attg[g*n+v]={el_gA,el_gB} (src side),
//   erg[g*n+v]={er_gA,er_gB} (dst side), and fp8 feature table fb8[n][256]:
//   bytes [0,128)=fs row e4m3, [128,256)=fd row e4m3 (gfx950 hw convert).
// hist: XCD-partitioned counting, int4 edge reads.
// graph gats: g0:(0,2) g1:(1,3) g2:(4,6) g3:(5,7)
// ---------------------------------------------------------------------------
__global__ __launch_bounds__(256) void prep_hist_kernel(const float* __restrict__ fs,
    const float* __restrict__ fd, const float* __restrict__ wl, const float* __restrict__ wr,
    float2* __restrict__ attg, float2* __restrict__ erg, uchar_t* __restrict__ fb8,
    const int* __restrict__ ia_s, const int* __restrict__ ia_d,
    const int* __restrict__ ie_s, const int* __restrict__ ie_d,
    int* __restrict__ counts, int n, int e, int n8, int npb, int G) {
  int b = blockIdx.x;
  if (b < npb) {
    int wid  = (b*256 + threadIdx.x) >> 6;
    int lane = threadIdx.x & 63;
    if (wid >= n) return;
    float2 s = *(const float2*)(fs + (size_t)wid*128 + lane*2);
    float2 d = *(const float2*)(fd + (size_t)wid*128 + lane*2);
    unsigned ps = (unsigned)__builtin_amdgcn_cvt_pk_fp8_f32(s.x, s.y, 0, false);
    unsigned pd = (unsigned)__builtin_amdgcn_cvt_pk_fp8_f32(d.x, d.y, 0, false);
    *(ushort_t*)(fb8 + (size_t)wid*256 + lane*2) = (ushort_t)(ps & 0xffffu);
    *(ushort_t*)(fb8 + (size_t)wid*256 + 128 + lane*2) = (ushort_t)(pd & 0xffffu);
    float elv[8], erv[8];
#pragma unroll
    for (int i = 0; i < 8; ++i) {
      float2 wlv = *(const float2*)(wl + i*128 + lane*2);
      float2 wrv = *(const float2*)(wr + i*128 + lane*2);
      bool use_s = (i==0)||(i==1)||(i==4)||(i==5);
      float xx = use_s ? s.x : d.x;
      float xy = use_s ? s.y : d.y;
      float vl = xx*wlv.x + xy*wlv.y;
      float vr = d.x*wrv.x + d.y*wrv.y;
#pragma unroll
      for (int off = 32; off; off >>= 1) { vl += __shfl_xor(vl, off); vr += __shfl_xor(vr, off); }
      elv[i] = vl; erv[i] = vr;
    }
    if (lane == 0) {
      attg[0*(size_t)n + wid] = make_float2(elv[0], elv[2]);
      attg[1*(size_t)n + wid] = make_float2(elv[1], elv[3]);
      attg[2*(size_t)n + wid] = make_float2(elv[4], elv[6]);
      attg[3*(size_t)n + wid] = make_float2(elv[5], elv[7]);
      erg[0*(size_t)n + wid] = make_float2(erv[0], erv[2]);
      erg[1*(size_t)n + wid] = make_float2(erv[1], erv[3]);
      erg[2*(size_t)n + wid] = make_float2(erv[4], erv[6]);
      erg[3*(size_t)n + wid] = make_float2(erv[5], erv[7]);
    }
  } else {
    int bid = b - npb;
    int x = bid & 7;
    int lo = x*n8, hi = lo + n8; if (hi > n) hi = n;
    int tid = (bid >> 3)*256 + threadIdx.x;
    int nthr = G << 8;
#pragma unroll
    for (int g = 0; g < 4; ++g) {
      const int* dp = (g==0) ? ia_d : (g==1) ? ie_d : (g==2) ? ia_s : ie_s;
      int bo = g*n;
      for (int i = tid*4; i < e; i += nthr*4) {
        if (i + 4 <= e) {
          int4 d4 = *(const int4*)(dp + i);
          if (d4.x >= lo && d4.x < hi) atomicAdd(&counts[bo + d4.x], 1);
          if (d4.y >= lo && d4.y < hi) atomicAdd(&counts[bo + d4.y], 1);
          if (d4.z >= lo && d4.z < hi) atomicAdd(&counts[bo + d4.z], 1);
          if (d4.w >= lo && d4.w < hi) atomicAdd(&counts[bo + d4.w], 1);
        } else {
          for (int q = i; q < e; ++q) {
            int dv = dp[q];
            if (dv >= lo && dv < hi) atomicAdd(&counts[bo + dv], 1);
          }
        }
      }
    }
  }
}

// ---------------------------------------------------------------------------
// K3: per-1024-chunk local exclusive scan; bsums[chunk] = chunk total.
// ---------------------------------------------------------------------------
__global__ __launch_bounds__(256) void scan_local_kernel(const int* __restrict__ counts,
    int* __restrict__ rowptr, int* __restrict__ bsums, int total) {
  __shared__ int sh[256];
  int base = blockIdx.x*1024;
  int tid = threadIdx.x;
  int v[4]; int s = 0;
#pragma unroll
  for (int q = 0; q < 4; ++q) { int idx = base + tid*4 + q; int x = (idx < total) ? counts[idx] : 0; v[q] = x; s += x; }
  sh[tid] = s; __syncthreads();
  for (int off = 1; off < 256; off <<= 1) {
    int t2 = (tid >= off) ? sh[tid-off] : 0;
    __syncthreads();
    sh[tid] += t2;
    __syncthreads();
  }
  if (tid == 255) bsums[blockIdx.x] = sh[255];
  int run = sh[tid] - s;
#pragma unroll
  for (int q = 0; q < 4; ++q) { int idx = base + tid*4 + q; if (idx < total) rowptr[idx] = run; run += v[q]; }
}

// ---------------------------------------------------------------------------
// K4: finish scan. Every block redundantly scans bsums (nb<=1024) in LDS,
// then fixes up its 512 rowptr entries AND writes cursor.
// ---------------------------------------------------------------------------
__global__ __launch_bounds__(512) void scan_finish_kernel(int* __restrict__ rowptr,
    int* __restrict__ cursor, const int* __restrict__ bsums, int total, int nb, int grand) {
  __shared__ int sb[1024];
  __shared__ int ps[512];
  int tid = threadIdx.x;
  int v0 = (2*tid   < nb) ? bsums[2*tid]   : 0;
  int v1 = (2*tid+1 < nb) ? bsums[2*tid+1] : 0;
  int s = v0 + v1;
  ps[tid] = s; __syncthreads();
  for (int off = 1; off < 512; off <<= 1) {
    int t2 = (tid >= off) ? ps[tid-off] : 0;
    __syncthreads();
    ps[tid] += t2;
    __syncthreads();
  }
  int excl = ps[tid] - s;
  sb[2*tid] = excl; sb[2*tid+1] = excl + v0;
  __syncthreads();
  int idx = blockIdx.x*512 + tid;
  if (idx < total) {
    int v = rowptr[idx] + sb[idx >> 10];
    rowptr[idx] = v;
    cursor[idx] = v;
  }
  if (idx == total) rowptr[total] = grand;
}

// ---------------------------------------------------------------------------
// K5: fill + attention-weight precompute. cursor preloaded with rowptr.
// XCD-partitioned, int4 edge reads. Per in-range edge: attg[g*n+s] (8B, per-
// graph 800KB table -> L2-resident), erg[g*n+d] (partition-local, hot),
// leakyrelu+exp both gats, pack epk[pos] = {s, bf16(pa)|bf16(pb)<<16}.
// ---------------------------------------------------------------------------
__global__ __launch_bounds__(256) void fill_kernel(const int* __restrict__ ia_s,
    const int* __restrict__ ia_d, const int* __restrict__ ie_s, const int* __restrict__ ie_d,
    const float2* __restrict__ attg, const float2* __restrict__ erg,
    int* __restrict__ cursor, int2* __restrict__ epk,
    int n, int e, int n8, int G) {
  int bid = blockIdx.x;
  int x = bid & 7;
  int lo = x*n8, hi = lo + n8; if (hi > n) hi = n;
  int tid = (bid >> 3)*256 + threadIdx.x;
  int nthr = G << 8;
#pragma unroll
  for (int g = 0; g < 4; ++g) {
    const int* dp = (g==0) ? ia_d : (g==1) ? ie_d : (g==2) ? ia_s : ie_s;
    const int* sp = (g==0) ? ia_s : (g==1) ? ie_s : (g==2) ? ia_d : ie_d;
    int bo = g*n;
    const float2* ag = attg + (size_t)g*n;
    const float2* eg = erg + (size_t)g*n;
    for (int i = tid*4; i < e; i += nthr*4) {
      int lim = (i + 4 <= e) ? 4 : (e - i);
      if (lim == 4) {
        int4 d4 = *(const int4*)(dp + i);
        bool m0 = d4.x >= lo && d4.x < hi;
        bool m1 = d4.y >= lo && d4.y < hi;
        bool m2 = d4.z >= lo && d4.z < hi;
        bool m3 = d4.w >= lo && d4.w < hi;
        if (m0 | m1 | m2 | m3) {
          int4 s4 = *(const int4*)(sp + i);
          int dv[4] = {d4.x, d4.y, d4.z, d4.w};
          int sv[4] = {s4.x, s4.y, s4.z, s4.w};
          bool mv[4] = {m0, m1, m2, m3};
#pragma unroll
          for (int q = 0; q < 4; ++q) {
            if (mv[q]) {
              int dd = dv[q], ss = sv[q];
              float2 a2 = ag[ss];
              float2 e2 = eg[dd];
              float ea = a2.x + e2.x;
              float eb = a2.y + e2.y;
              ea = (ea > 0.f) ? ea : 0.2f*ea;
              eb = (eb > 0.f) ? eb : 0.2f*eb;
              unsigned p2 = (unsigned)f2bf(__expf(ea)) | ((unsigned)f2bf(__expf(eb)) << 16);
              int pos = atomicAdd(&cursor[bo + dd], 1);
              epk[pos] = make_int2(ss, (int)p2);
            }
          }
        }
      } else {
        for (int q = i; q < e; ++q) {
          int dd = dp[q];
          if (dd >= lo && dd < hi) {
            int ss = sp[q];
            float2 a2 = ag[ss];
            float2 e2 = eg[dd];
            float ea = a2.x + e2.x;
            float eb = a2.y + e2.y;
            ea = (ea > 0.f) ? ea : 0.2f*ea;
            eb = (eb > 0.f) ? eb : 0.2f*eb;
            unsigned p2 = (unsigned)f2bf(__expf(ea)) | ((unsigned)f2bf(__expf(eb)) << 16);
            int pos = atomicAdd(&cursor[bo + dd], 1);
            epk[pos] = make_int2(ss, (int)p2);
          }
        }
      }
    }
  }
}

// ---------------------------------------------------------------------------
// K6: fused aggregation + MFMA GEMM + epilogue. Block = 16 dsts, 8 waves.
// Agg: wave w -> graph g=w>>1, dst-subset w&1 (8 dsts); lanes split 32|32
//   into 2 edge slots; within a slot, lane covers 8 features = 8 fp8 bytes
//   (u32x2 load from fb8), l<16 -> fs half/pa, l>=16 -> fd half/pb.
//   Inner loop: 8B epk read -> 8B fp8 row gather -> hw cvt_pk_f32_fp8 ->
//   pk_fma. 2-stage pipelined. Merge halves via shfl_xor(32).
// MFMA: wave w owns col-frag f=w, K=1024 over XOR-swizzled LDS A-tile.
// Epilogue: out = C + rc*fd(f32 stream) + bsum, written once.
// ---------------------------------------------------------------------------
__global__ __launch_bounds__(512) void fused_kernel(const uchar_t* __restrict__ fb8,
    const int* __restrict__ rowptr, const int2* __restrict__ epk,
    const ushort_t* __restrict__ Wf, const float* __restrict__ lam,
    const float* __restrict__ fd, const float* __restrict__ bsum,
    float* __restrict__ out, int n) {
  __shared__ ushort_t As[16*1024];
  int t = threadIdx.x, w = t >> 6, lane = t & 63;
  int base = blockIdx.x*16;
  int g = w >> 1;
  int half = lane >> 5;
  int l    = lane & 31;
  int typ  = (l >> 4) & 1;
  int boff = typ*128 + (l & 15)*8;      // byte offset of this lane's 8 features

  for (int i = 0; i < 8; ++i) {
    int di = (w & 1)*8 + i;
    int d = base + di; if (d >= n) d = n - 1;
    int row = rowptr[(size_t)g*n + d], end = rowptr[(size_t)g*n + d + 1];
    f32x2 acc0 = {0.f,0.f}, acc1 = {0.f,0.f}, acc2 = {0.f,0.f}, acc3 = {0.f,0.f};
    float den = 0.f;
    int e2 = row + half;
    int2 eC = {0, 0}; u32x2 uC = {0,0};
    if (e2 < end) {
      eC = epk[e2];
      uC = *reinterpret_cast<const u32x2*>(fb8 + (size_t)eC.x*256 + boff);
    }
    while (e2 < end) {
      int eN = e2 + 2;
      int2 eT = eC; u32x2 uN = uC;
      if (eN < end) {
        eT = epk[eN];
        uN = *reinterpret_cast<const u32x2*>(fb8 + (size_t)eT.x*256 + boff);
      }
      unsigned p2 = (unsigned)eC.y;
      float p = typ ? __uint_as_float(p2 & 0xffff0000u)
                    : __uint_as_float(p2 << 16);
      den += p;
      f32x2 pv = {p, p};
      f32x2 x0 = __builtin_amdgcn_cvt_pk_f32_fp8((int)uC[0], false);
      f32x2 x1 = __builtin_amdgcn_cvt_pk_f32_fp8((int)uC[0], true);
      f32x2 x2 = __builtin_amdgcn_cvt_pk_f32_fp8((int)uC[1], false);
      f32x2 x3 = __builtin_amdgcn_cvt_pk_f32_fp8((int)uC[1], true);
      acc0 += pv*x0; acc1 += pv*x1; acc2 += pv*x2; acc3 += pv*x3;
      e2 = eN; eC = eT; uC = uN;
    }
    den += __shfl_xor(den, 32);
    acc0[0] += __shfl_xor(acc0[0], 32); acc0[1] += __shfl_xor(acc0[1], 32);
    acc1[0] += __shfl_xor(acc1[0], 32); acc1[1] += __shfl_xor(acc1[1], 32);
    acc2[0] += __shfl_xor(acc2[0], 32); acc2[1] += __shfl_xor(acc2[1], 32);
    acc3[0] += __shfl_xor(acc3[0], 32); acc3[1] += __shfl_xor(acc3[1], 32);
    if (half == 0) {
      float r = 1.f/fmaxf(den, 1e-9f);
      u16x8 o;
      o[0]=f2bf(acc0[0]*r); o[1]=f2bf(acc0[1]*r); o[2]=f2bf(acc1[0]*r); o[3]=f2bf(acc1[1]*r);
      o[4]=f2bf(acc2[0]*r); o[5]=f2bf(acc2[1]*r); o[6]=f2bf(acc3[0]*r); o[7]=f2bf(acc3[1]*r);
      int k = g*256 + l*8;
      int idx = di*1024 + (k ^ ((di & 7) << 3));
      *reinterpret_cast<u16x8*>(As + idx) = o;
    }
  }
  __syncthreads();

  int lr = lane & 15, lg = lane >> 4;
  f32x4 c0 = {0.f,0.f,0.f,0.f};
#pragma unroll
  for (int ks = 0; ks < 32; ++ks) {
    int kc = ks*32 + lg*8;
    int idx = lr*1024 + (kc ^ ((lr & 7) << 3));
    bf16x8 a = *reinterpret_cast<const bf16x8*>(As + idx);
    int wp = ks >> 3, sub = ks & 7;
    int gg = ((sub >= 4) ? 2 : 0) + ((wp < 2) ? wp : wp + 2);
    int kk = sub & 3;
    const ushort_t* bp = Wf + (((size_t)(gg*4 + kk)*8 + w)*64 + lane)*8;
    bf16x8 b0 = *reinterpret_cast<const bf16x8*>(bp);
    c0 = __builtin_amdgcn_mfma_f32_16x16x32_bf16(a, b0, c0, 0, 0, 0);
  }
  float rc = 2.f*(lam[0] + lam[1] + lam[2] + lam[3]);
  int gc = w*16 + lr;
#pragma unroll
  for (int r2 = 0; r2 < 4; ++r2) {
    int gr = base + lg*4 + r2;
    if (gr < n) {
      size_t o = (size_t)gr*128 + gc;
      out[o] = c0[r2] + rc*fd[o] + bsum[gc];
    }
  }
}

// ---------------------------------------------------------------------------
extern "C" void kernel_launch(void* const* d_in, const int* in_sizes, int n_in,
                              void* d_out, int out_size, void* d_ws, size_t ws_size,
                              hipStream_t stream) {
  const float* fs  = (const float*)d_in[0];
  const float* fd  = (const float*)d_in[1];
  const int* ia_s  = (const int*)d_in[2];
  const int* ia_d  = (const int*)d_in[3];
  const int* ie_s  = (const int*)d_in[4];
  const int* ie_d  = (const int*)d_in[5];
  const float* W   = (const float*)d_in[6];
  const float* al  = (const float*)d_in[7];
  const float* ar  = (const float*)d_in[8];
  const float* bias= (const float*)d_in[9];
  const float* lam = (const float*)d_in[10];
  int n = in_sizes[0] / 128;
  int e = in_sizes[2];
  float* out = (float*)d_out;

  char* ws = (char*)d_ws;
  size_t off = 0;
  auto alloc = [&](size_t bytes) -> char* { char* p = ws + off; off += (bytes + 255) & ~(size_t)255; return p; };
  float* wl      = (float*)alloc((size_t)8*128*4);
  float* wr      = (float*)alloc((size_t)8*128*4);
  float* bsum    = (float*)alloc(128*4);
  float2* attg   = (float2*)alloc((size_t)4*n*8);
  float2* erg    = (float2*)alloc((size_t)4*n*8);
  int*   counts  = (int*)alloc((size_t)4*n*4);          // reused as cursor
  int*   rowptr  = (int*)alloc(((size_t)4*n + 1)*4);
  int*   bsums   = (int*)alloc(4096);
  int2*  epk     = (int2*)alloc((size_t)4*e*8);
  ushort_t* Wf   = (ushort_t*)alloc((size_t)8*128*128*2);
  uchar_t* fb8   = (uchar_t*)alloc((size_t)n*256);
  (void)ws_size; (void)n_in; (void)out_size;

  int n8 = (n + 7)/8;
  int total = 4*n;
  int nb = (total + 1023)/1024;                 // scan chunks (<=1024 supported)
  int nZ = (total + 1023)/1024;                 // zero-blocks (1024 ints each)
  int npb = (n + 3)/4;                          // prep blocks
  int G = 160;                                  // edge-scan groups per partition

  hipLaunchKernelGGL(init_kernel, dim3(72 + nZ), dim3(256), 0, stream,
                     W, al, ar, bias, lam, wl, wr, bsum, Wf, counts, n);
  hipLaunchKernelGGL(prep_hist_kernel, dim3(npb + 8*G), dim3(256), 0, stream,
                     fs, fd, wl, wr, attg, erg, fb8, ia_s, ia_d, ie_s, ie_d,
                     counts, n, e, n8, npb, G);
  hipLaunchKernelGGL(scan_local_kernel, dim3(nb), dim3(256), 0, stream,
                     counts, rowptr, bsums, total);
  hipLaunchKernelGGL(scan_finish_kernel, dim3((total + 512)/512), dim3(512), 0, stream,
                     rowptr, counts, bsums, total, nb, 4*e);
  hipLaunchKernelGGL(fill_kernel, dim3(8*G), dim3(256), 0, stream,
                     ia_s, ia_d, ie_s, ie_d, attg, erg, counts, epk, n, e, n8, G);
  hipLaunchKernelGGL(fused_kernel, dim3((n+15)/16), dim3(512), 0, stream,
                     fb8, rowptr, epk, Wf, lam, fd, bsum, out, n);
}